// Round 2
// baseline (755.447 us; speedup 1.0000x reference)
//
#include <hip/hip_runtime.h>
#include <hip/hip_bf16.h>
#include <math.h>

#define DEV __device__ __forceinline__
DEV float silu_f(float x) { return x / (1.0f + __expf(-x)); }

constexpr int Bc = 8, Nc = 256, BNc = 2048, Ec = 16384;
constexpr int Hc = 256, NHc = 8, HDc = 32, VDc = 8;

// ---------------- LayerNorm: one block per row ----------------
__global__ __launch_bounds__(256) void ln_k(const float* __restrict__ x,
    const float* __restrict__ w, const float* __restrict__ b,
    float* __restrict__ xn) {
  int row = blockIdx.x, h = threadIdx.x;
  float v = x[(size_t)row * Hc + h];
  __shared__ float sm[256];
  sm[h] = v; __syncthreads();
  for (int s = 128; s > 0; s >>= 1) { if (h < s) sm[h] += sm[h + s]; __syncthreads(); }
  float mu = sm[0] * (1.0f / 256.0f);
  __syncthreads();
  float d = v - mu;
  sm[h] = d * d; __syncthreads();
  for (int s = 128; s > 0; s >>= 1) { if (h < s) sm[h] += sm[h + s]; __syncthreads(); }
  float var = sm[0] * (1.0f / 256.0f);
  float r = rsqrtf(var + 1e-5f);
  xn[(size_t)row * Hc + h] = d * r * w[h] + b[h];
}

// ---------------- Generic tiled GEMM: C = act(A @ W + bias) ----------------
// A: (M,K) row-major, W: (K,N) row-major, C: (M,N). All fp32.
// Block: 256 threads, 64x64 tile, 4x4 accum per thread. M%64==0, N%64==0, K%16==0.
template <int ACT>
__global__ __launch_bounds__(256) void gemm_k(
    const float* __restrict__ A, const float* __restrict__ W,
    const float* __restrict__ bias, float* __restrict__ C,
    int M, int K, int N) {
  __shared__ float At[16][68];  // [k][m] transposed A tile
  __shared__ float Wt[16][68];  // [k][n]
  int tid = threadIdx.x;
  int tx = tid & 15, ty = tid >> 4;
  int m0 = blockIdx.x * 64, n0 = blockIdx.y * 64;
  float acc[4][4] = {};
  for (int k0 = 0; k0 < K; k0 += 16) {
#pragma unroll
    for (int r = 0; r < 4; ++r) {
      int idx = r * 256 + tid;
      int ar = idx >> 4, ac = idx & 15;
      At[ac][ar] = A[(size_t)(m0 + ar) * K + (k0 + ac)];
    }
#pragma unroll
    for (int r = 0; r < 4; ++r) {
      int idx = r * 256 + tid;
      int wr = idx >> 6, wc = idx & 63;
      Wt[wr][wc] = W[(size_t)(k0 + wr) * N + (n0 + wc)];
    }
    __syncthreads();
#pragma unroll
    for (int kk = 0; kk < 16; ++kk) {
      float4 a = *(const float4*)&At[kk][ty * 4];
      float4 bv = *(const float4*)&Wt[kk][tx * 4];
      float av[4] = {a.x, a.y, a.z, a.w};
      float bb[4] = {bv.x, bv.y, bv.z, bv.w};
#pragma unroll
      for (int i = 0; i < 4; ++i)
#pragma unroll
        for (int j = 0; j < 4; ++j) acc[i][j] += av[i] * bb[j];
    }
    __syncthreads();
  }
#pragma unroll
  for (int i = 0; i < 4; ++i) {
    int row = m0 + ty * 4 + i;
#pragma unroll
    for (int j = 0; j < 4; ++j) {
      int col = n0 + tx * 4 + j;
      float v = acc[i][j];
      if (bias) v += bias[col];
      if (ACT) v = silu_f(v);
      C[(size_t)row * N + col] = v;
    }
  }
}

// ---------------- Fused attention per (b,h): out = (silu(QK^T/sqrt32) @ V)/N ----------------
__global__ __launch_bounds__(256) void attn_k(
    const float* __restrict__ qb, const float* __restrict__ kb,
    const float* __restrict__ vb, float* __restrict__ ob) {
  int b = blockIdx.x >> 3, h = blockIdx.x & 7;
  int i = threadIdx.x;
  __shared__ float Ks[256 * 32];
  __shared__ float Vs[256 * 32];
  size_t rowoff = ((size_t)(b * Nc + i)) * Hc + h * HDc;
#pragma unroll
  for (int d4 = 0; d4 < 8; ++d4) {
    *(float4*)&Ks[i * 32 + d4 * 4] = *(const float4*)&kb[rowoff + d4 * 4];
    *(float4*)&Vs[i * 32 + d4 * 4] = *(const float4*)&vb[rowoff + d4 * 4];
  }
  float q[32], acc[32];
#pragma unroll
  for (int d4 = 0; d4 < 8; ++d4)
    *(float4*)&q[d4 * 4] = *(const float4*)&qb[rowoff + d4 * 4];
#pragma unroll
  for (int d = 0; d < 32; ++d) acc[d] = 0.f;
  __syncthreads();
  for (int j = 0; j < 256; ++j) {
    float s = 0.f;
#pragma unroll
    for (int d = 0; d < 32; ++d) s += q[d] * Ks[j * 32 + d];
    s *= 0.17677669529663687f;  // 1/sqrt(32)
    float p = silu_f(s);
#pragma unroll
    for (int d = 0; d < 32; ++d) acc[d] += p * Vs[j * 32 + d];
  }
#pragma unroll
  for (int d = 0; d < 32; ++d) ob[rowoff + d] = acc[d] * (1.0f / 256.0f);
}

// ---------------- vec_sum[n,h] = sum_vd vp[n,vd,:H][h] ----------------
__global__ __launch_bounds__(256) void vecsum_k(const float* __restrict__ vp,
                                                float* __restrict__ vs) {
  int idx = blockIdx.x * 256 + threadIdx.x;
  int n = idx >> 8, h = idx & 255;
  float s = 0.f;
#pragma unroll
  for (int vd = 0; vd < 8; ++vd) s += vp[((size_t)n * 8 + vd) * 512 + h];
  vs[idx] = s;
}

// ---------------- v_j = v[src]*cut*dv ; x_agg += (scatter) ----------------
__global__ __launch_bounds__(256) void vj_k(
    const float* __restrict__ v, const float* __restrict__ dv,
    const int* __restrict__ ei, const float* __restrict__ r_ij,
    float* __restrict__ vj, float* __restrict__ xagg) {
  int e = blockIdx.x, h = threadIdx.x;
  int src = ei[e], dst = ei[Ec + e];
  float r = r_ij[e];
  float cut = (r < 5.0f) ? 0.5f * (cosf(0.6283185307179586f * r) + 1.0f) : 0.0f;
  float val = v[(size_t)src * Hc + h] * cut * dv[(size_t)e * Hc + h];
  vj[(size_t)e * Hc + h] = val;
  atomicAdd(&xagg[(size_t)dst * Hc + h], val);
}

// ---------------- vec_j scatter: vec_agg += vec[src]*s1 + s2*d_ij ----------------
__global__ __launch_bounds__(256) void scatter_k(
    const float* __restrict__ vec, const float* __restrict__ s12,
    const float* __restrict__ d_ij, const int* __restrict__ ei,
    float* __restrict__ vagg) {
  int blk = blockIdx.x;
  int e = blk >> 3, vd = blk & 7, h = threadIdx.x;
  int src = ei[e], dst = ei[Ec + e];
  float s1 = s12[(size_t)e * 512 + h];
  float s2 = s12[(size_t)e * 512 + 256 + h];
  float dd = d_ij[(size_t)e * VDc + vd];
  float vv = vec[((size_t)src * VDc + vd) * Hc + h];
  atomicAdd(&vagg[((size_t)dst * VDc + vd) * Hc + h], vv * s1 + s2 * dd);
}

// ---------------- dx = vec_sum*o2 + o3 ----------------
__global__ __launch_bounds__(256) void dx_k(const float* __restrict__ vs,
                                            const float* __restrict__ o,
                                            float* __restrict__ out) {
  int idx = blockIdx.x * 256 + threadIdx.x;
  int row = idx >> 8, col = idx & 255;
  float o2 = o[(size_t)row * 768 + 256 + col];
  float o3 = o[(size_t)row * 768 + 512 + col];
  out[idx] = vs[idx] * o2 + o3;
}

// ---------------- dvec = vec3*o1 + vec_agg ----------------
__global__ __launch_bounds__(256) void dvec_k(const float* __restrict__ vp,
                                              const float* __restrict__ o,
                                              const float* __restrict__ vagg,
                                              float* __restrict__ out) {
  size_t idx = (size_t)blockIdx.x * 256 + threadIdx.x;
  int nv = (int)(idx >> 8), h = (int)(idx & 255);
  int n = nv >> 3;
  float v3 = vp[(size_t)nv * 512 + 256 + h];
  float o1 = o[(size_t)n * 768 + h];
  out[idx] = v3 * o1 + vagg[idx];
}

// ---------------- df = fW * (sum t1*t2 - p1*p2)  (rejection identity) ----------------
__global__ __launch_bounds__(256) void df_k(
    const float* __restrict__ Tt, const float* __restrict__ Ts,
    const float* __restrict__ d_ij, const float* __restrict__ fW,
    const int* __restrict__ ei, float* __restrict__ out) {
  int e = blockIdx.x, h = threadIdx.x;
  int src = ei[e], dst = ei[Ec + e];
  float S = 0.f, p1 = 0.f, p2 = 0.f;
#pragma unroll
  for (int vd = 0; vd < 8; ++vd) {
    float t1 = Tt[((size_t)dst * 8 + vd) * Hc + h];
    float t2 = Ts[((size_t)src * 8 + vd) * Hc + h];
    float dd = d_ij[(size_t)e * 8 + vd];
    S += t1 * t2; p1 += t1 * dd; p2 += t2 * dd;
  }
  out[(size_t)e * Hc + h] = fW[(size_t)e * Hc + h] * (S - p1 * p2);
}

extern "C" void kernel_launch(void* const* d_in, const int* in_sizes, int n_in,
                              void* d_out, int out_size, void* d_ws, size_t ws_size,
                              hipStream_t stream) {
  const float* x    = (const float*)d_in[0];
  const float* vec  = (const float*)d_in[1];
  const int*   ei   = (const int*)d_in[2];
  const float* r_ij = (const float*)d_in[3];
  const float* f_ij = (const float*)d_in[4];
  const float* d_ij = (const float*)d_in[5];
  // d_in[6] = batch (unused by reference)
  const float* ln_w = (const float*)d_in[7];
  const float* ln_b = (const float*)d_in[8];
  const float* Wq   = (const float*)d_in[9];
  const float* Wk   = (const float*)d_in[10];
  const float* Wv   = (const float*)d_in[11];
  const float* Wao  = (const float*)d_in[12];
  const float* Wvec = (const float*)d_in[13];
  const float* Wdv  = (const float*)d_in[14];
  const float* bdv  = (const float*)d_in[15];
  const float* Ws   = (const float*)d_in[16];
  const float* bs   = (const float*)d_in[17];
  const float* Wo   = (const float*)d_in[18];
  const float* bo   = (const float*)d_in[19];
  const float* Wf   = (const float*)d_in[20];
  const float* bf_  = (const float*)d_in[21];
  const float* Wsrc = (const float*)d_in[22];
  const float* Wtrg = (const float*)d_in[23];

  char* ws = (char*)d_ws;
  float* xn    = (float*)(ws + 0);                  // 2048x256
  float* qb    = (float*)(ws + 2097152);            // 2048x256
  float* kb    = (float*)(ws + 4194304);            // 2048x256
  float* vvb   = (float*)(ws + 6291456);            // 2048x256
  float* attnv = (float*)(ws + 8388608);            // 2048x256
  float* vbuf  = (float*)(ws + 10485760);           // 2048x256 (after Wao)
  float* vsum  = (float*)(ws + 12582912);           // 2048x256
  float* xagg  = (float*)(ws + 14680064);           // 2048x256
  float* obuf  = (float*)(ws + 16777216);           // 2048x768
  float* vagg  = (float*)(ws + 23068672);           // 16384x256
  float* dv    = (float*)(ws + 39845888);           // 16384x256
  float* vp    = (float*)(ws + 56623104);           // 16384x512
  float* vj    = (float*)(ws + 90177536);           // 16384x256
  float* s12   = (float*)(ws + 106954752);          // 16384x512
  float* fW    = (float*)(ws + 140509184);          // 16384x256
  float* Ttrg  = (float*)(ws + 157286400);          // 16384x256 (nodes x VD x H)
  float* Tsrc  = (float*)(ws + 174063616);          // 16384x256
  // total ws usage: 190,840,832 bytes

  float* out_dx   = (float*)d_out;                  // 2048*256
  float* out_dvec = (float*)d_out + 524288;         // 2048*8*256
  float* out_df   = (float*)d_out + 4718592;        // 16384*256

  // zero accumulators (ws is poisoned before every call)
  hipMemsetAsync(xagg, 0, 2097152, stream);
  hipMemsetAsync(vagg, 0, 16777216, stream);

  // 1. LayerNorm
  ln_k<<<BNc, 256, 0, stream>>>(x, ln_w, ln_b, xn);

  // 2. q/k/v projections
  gemm_k<0><<<dim3(32, 4), 256, 0, stream>>>(xn, Wq, nullptr, qb, BNc, Hc, Hc);
  gemm_k<0><<<dim3(32, 4), 256, 0, stream>>>(xn, Wk, nullptr, kb, BNc, Hc, Hc);
  gemm_k<0><<<dim3(32, 4), 256, 0, stream>>>(xn, Wv, nullptr, vvb, BNc, Hc, Hc);

  // 3. attention per (b,h)
  attn_k<<<Bc * NHc, 256, 0, stream>>>(qb, kb, vvb, attnv);

  // 4. v = attnv @ Wao
  gemm_k<0><<<dim3(32, 4), 256, 0, stream>>>(attnv, Wao, nullptr, vbuf, BNc, Hc, Hc);

  // 5. dv = silu(f_ij @ Wdv + bdv)
  gemm_k<1><<<dim3(256, 4), 256, 0, stream>>>(f_ij, Wdv, bdv, dv, Ec, Hc, Hc);

  // 6. vp = vec @ Wvec ; vec_sum
  gemm_k<0><<<dim3(256, 8), 256, 0, stream>>>(vec, Wvec, nullptr, vp, BNc * VDc, Hc, 2 * Hc);
  vecsum_k<<<2048, 256, 0, stream>>>(vp, vsum);

  // 7. v_j + fused x_agg scatter
  vj_k<<<Ec, 256, 0, stream>>>(vbuf, dv, ei, r_ij, vj, xagg);

  // 8. s12 = silu(v_j @ Ws + bs)
  gemm_k<1><<<dim3(256, 8), 256, 0, stream>>>(vj, Ws, bs, s12, Ec, Hc, 2 * Hc);

  // 9. vec_agg scatter
  scatter_k<<<Ec * VDc, 256, 0, stream>>>(vec, s12, d_ij, ei, vagg);

  // 10. o = x_agg @ Wo + bo
  gemm_k<0><<<dim3(32, 12), 256, 0, stream>>>(xagg, Wo, bo, obuf, BNc, Hc, 3 * Hc);

  // 11. dx, dvec
  dx_k<<<2048, 256, 0, stream>>>(vsum, obuf, out_dx);
  dvec_k<<<16384, 256, 0, stream>>>(vp, obuf, vagg, out_dvec);

  // 12. df path: per-node GEMMs (gather commutes with the node GEMM)
  gemm_k<1><<<dim3(256, 4), 256, 0, stream>>>(f_ij, Wf, bf_, fW, Ec, Hc, Hc);
  gemm_k<0><<<dim3(256, 4), 256, 0, stream>>>(vec, Wtrg, nullptr, Ttrg, BNc * VDc, Hc, Hc);
  gemm_k<0><<<dim3(256, 4), 256, 0, stream>>>(vec, Wsrc, nullptr, Tsrc, BNc * VDc, Hc, Hc);
  df_k<<<Ec, 256, 0, stream>>>(Ttrg, Tsrc, d_ij, fW, ei, out_df);

  (void)in_sizes; (void)n_in; (void)out_size; (void)ws_size;
}

// Round 3
// 506.403 us; speedup vs baseline: 1.4918x; 1.4918x over previous
//
#include <hip/hip_runtime.h>
#include <hip/hip_bf16.h>
#include <math.h>

typedef __hip_bfloat16 bf16;
#define DEV __device__ __forceinline__
DEV float silu_f(float x) { return x / (1.0f + __expf(-x)); }
DEV float toF(bf16 x) { return __bfloat162float(x); }
DEV void storeF(float* p, float v) { *p = v; }
DEV void storeF(bf16* p, float v) { *p = __float2bfloat16(v); }

constexpr int Bc = 8, Nc = 256, BNc = 2048, Ec = 16384;
constexpr int Hc = 256, NHc = 8, HDc = 32, VDc = 8;

typedef __attribute__((ext_vector_type(8))) short short8;
typedef __attribute__((ext_vector_type(4))) float floatx4;

// async global->LDS, 16B per lane. LDS dest must be wave-uniform base + lane*16.
DEV void async_copy16(const void* g, void* l) {
  __builtin_amdgcn_global_load_lds(
      (const __attribute__((address_space(1))) void*)g,
      (__attribute__((address_space(3))) void*)l, 16, 0, 0);
}

// ---------------- weight prep: out[n*K+k] = bf16(in[k*N+n]) ----------------
__global__ __launch_bounds__(256) void wprep_k(const float* __restrict__ in,
                                               bf16* __restrict__ out,
                                               int K, int N) {
  __shared__ float t[32][33];
  int k0 = blockIdx.x * 32, n0 = blockIdx.y * 32;
  int tx = threadIdx.x & 31, ty = threadIdx.x >> 5;  // ty in 0..7
#pragma unroll
  for (int i = 0; i < 32; i += 8)
    t[ty + i][tx] = in[(size_t)(k0 + ty + i) * N + n0 + tx];
  __syncthreads();
#pragma unroll
  for (int i = 0; i < 32; i += 8)
    out[(size_t)(n0 + ty + i) * K + k0 + tx] = __float2bfloat16(t[tx][ty + i]);
}

// ---------------- fp32 -> bf16 convert (n multiple of 1024) ----------------
__global__ __launch_bounds__(256) void cvt_k(const float* __restrict__ in,
                                             bf16* __restrict__ out, int n) {
  int i = (blockIdx.x * 256 + threadIdx.x) * 4;
  float4 v = *(const float4*)&in[i];
  union { bf16 b[4]; uint2 u; } o;
  o.b[0] = __float2bfloat16(v.x); o.b[1] = __float2bfloat16(v.y);
  o.b[2] = __float2bfloat16(v.z); o.b[3] = __float2bfloat16(v.w);
  *(uint2*)&out[i] = o.u;
}

// ---------------- LayerNorm -> bf16 ----------------
__global__ __launch_bounds__(256) void ln_k(const float* __restrict__ x,
    const float* __restrict__ w, const float* __restrict__ b,
    bf16* __restrict__ xn) {
  int row = blockIdx.x, h = threadIdx.x;
  float v = x[(size_t)row * Hc + h];
  __shared__ float sm[256];
  sm[h] = v; __syncthreads();
  for (int s = 128; s > 0; s >>= 1) { if (h < s) sm[h] += sm[h + s]; __syncthreads(); }
  float mu = sm[0] * (1.0f / 256.0f);
  __syncthreads();
  float d = v - mu;
  sm[h] = d * d; __syncthreads();
  for (int s = 128; s > 0; s >>= 1) { if (h < s) sm[h] += sm[h + s]; __syncthreads(); }
  float var = sm[0] * (1.0f / 256.0f);
  float r = rsqrtf(var + 1e-5f);
  xn[(size_t)row * Hc + h] = __float2bfloat16(d * r * w[h] + b[h]);
}

// ---------------- MFMA GEMM: C = act(A @ Bt^T + bias) ----------------
// A: (M,K) bf16 row-major. Bt: (N,K) bf16 row-major (i.e. B transposed).
// C: (M,N) fp32 or bf16. 128x128 tile, 256 threads (4 waves, 2x2 of 64x64).
// Requires M%128==0, N%128==0, K%32==0, K>=32.
template <int ACT, typename TC>
__global__ __launch_bounds__(256) void mgemm_k(
    const bf16* __restrict__ A, const bf16* __restrict__ Bt,
    const float* __restrict__ bias, TC* __restrict__ C,
    int M, int K, int N) {
  __shared__ bf16 Als[128 * 32];
  __shared__ bf16 Bls[128 * 32];
  int tid = threadIdx.x;
  int lane = tid & 63, w = tid >> 6;
  int m0 = blockIdx.x * 128, n0 = blockIdx.y * 128;
  int wm = (w & 1) * 64, wn = (w >> 1) * 64;
  int fm = lane & 15, g = lane >> 4;
  floatx4 acc[4][4] = {};
  for (int k0 = 0; k0 < K; k0 += 32) {
#pragma unroll
    for (int t = 0; t < 2; ++t) {
      int c = t * 256 + w * 64 + lane;     // chunk 0..511 (16B each)
      int r = c >> 2, q = c & 3;           // row 0..127, 16B-chunk in row
      bf16* ldsA = &Als[(t * 256 + w * 64) * 8 + lane * 8];  // uniform base + lane*16B
      bf16* ldsB = &Bls[(t * 256 + w * 64) * 8 + lane * 8];
      async_copy16(A + (size_t)(m0 + r) * K + k0 + q * 8, ldsA);
      async_copy16(Bt + (size_t)(n0 + r) * K + k0 + q * 8, ldsB);
    }
    __syncthreads();
    short8 af[4], bg[4];
#pragma unroll
    for (int i = 0; i < 4; ++i) {
      af[i] = *(const short8*)&Als[(wm + i * 16 + fm) * 32 + g * 8];
      bg[i] = *(const short8*)&Bls[(wn + i * 16 + fm) * 32 + g * 8];
    }
#pragma unroll
    for (int mi = 0; mi < 4; ++mi)
#pragma unroll
      for (int ni = 0; ni < 4; ++ni)
        acc[mi][ni] = __builtin_amdgcn_mfma_f32_16x16x32_bf16(
            af[mi], bg[ni], acc[mi][ni], 0, 0, 0);
    __syncthreads();
  }
#pragma unroll
  for (int mi = 0; mi < 4; ++mi) {
    int row0 = m0 + wm + mi * 16 + g * 4;
#pragma unroll
    for (int ni = 0; ni < 4; ++ni) {
      int col = n0 + wn + ni * 16 + fm;
      float bv = bias ? bias[col] : 0.0f;
#pragma unroll
      for (int r = 0; r < 4; ++r) {
        float v = acc[mi][ni][r] + bv;
        if (ACT) v = silu_f(v);
        storeF(&C[(size_t)(row0 + r) * N + col], v);
      }
    }
  }
}

// ---------------- attention per (b,h): out = bf16((silu(QK^T/sqrt32) @ V)/N) ----------------
__global__ __launch_bounds__(256) void attn_k(
    const float* __restrict__ qb, const float* __restrict__ kb,
    const float* __restrict__ vb, bf16* __restrict__ ob) {
  int b = blockIdx.x >> 3, h = blockIdx.x & 7;
  int i = threadIdx.x;
  __shared__ float Ks[256 * 32];
  __shared__ float Vs[256 * 32];
  size_t rowoff = ((size_t)(b * Nc + i)) * Hc + h * HDc;
#pragma unroll
  for (int d4 = 0; d4 < 8; ++d4) {
    *(float4*)&Ks[i * 32 + d4 * 4] = *(const float4*)&kb[rowoff + d4 * 4];
    *(float4*)&Vs[i * 32 + d4 * 4] = *(const float4*)&vb[rowoff + d4 * 4];
  }
  float q[32], acc[32];
#pragma unroll
  for (int d4 = 0; d4 < 8; ++d4)
    *(float4*)&q[d4 * 4] = *(const float4*)&qb[rowoff + d4 * 4];
#pragma unroll
  for (int d = 0; d < 32; ++d) acc[d] = 0.f;
  __syncthreads();
  for (int j = 0; j < 256; ++j) {
    float s = 0.f;
#pragma unroll
    for (int d = 0; d < 32; ++d) s += q[d] * Ks[j * 32 + d];
    s *= 0.17677669529663687f;
    float p = silu_f(s);
#pragma unroll
    for (int d = 0; d < 32; ++d) acc[d] += p * Vs[j * 32 + d];
  }
#pragma unroll
  for (int d = 0; d < 32; ++d)
    ob[rowoff + d] = __float2bfloat16(acc[d] * (1.0f / 256.0f));
}

// ---------------- vec_sum[n,h] = sum_vd vp[n,vd,h] ----------------
__global__ __launch_bounds__(256) void vecsum_k(const bf16* __restrict__ vp,
                                                float* __restrict__ vs) {
  int idx = blockIdx.x * 256 + threadIdx.x;
  int n = idx >> 8, h = idx & 255;
  float s = 0.f;
#pragma unroll
  for (int vd = 0; vd < 8; ++vd) s += toF(vp[((size_t)n * 8 + vd) * 512 + h]);
  vs[idx] = s;
}

// ---------------- v_j = v[src]*cut*dv ; x_agg += (scatter) ----------------
__global__ __launch_bounds__(256) void vj_k(
    const float* __restrict__ v, const bf16* __restrict__ dv,
    const int* __restrict__ ei, const float* __restrict__ r_ij,
    bf16* __restrict__ vj, float* __restrict__ xagg) {
  int e = blockIdx.x, h = threadIdx.x;
  int src = ei[e], dst = ei[Ec + e];
  float r = r_ij[e];
  float cut = (r < 5.0f) ? 0.5f * (cosf(0.6283185307179586f * r) + 1.0f) : 0.0f;
  float val = v[(size_t)src * Hc + h] * cut * toF(dv[(size_t)e * Hc + h]);
  vj[(size_t)e * Hc + h] = __float2bfloat16(val);
  atomicAdd(&xagg[(size_t)dst * Hc + h], val);
}

// ---------------- vec_agg += vec[src]*s1 + s2*d_ij ----------------
__global__ __launch_bounds__(256) void scatter_k(
    const float* __restrict__ vec, const bf16* __restrict__ s12,
    const float* __restrict__ d_ij, const int* __restrict__ ei,
    float* __restrict__ vagg) {
  int blk = blockIdx.x;
  int e = blk >> 3, vd = blk & 7, h = threadIdx.x;
  int src = ei[e], dst = ei[Ec + e];
  float s1 = toF(s12[(size_t)e * 512 + h]);
  float s2 = toF(s12[(size_t)e * 512 + 256 + h]);
  float dd = d_ij[(size_t)e * VDc + vd];
  float vv = vec[((size_t)src * VDc + vd) * Hc + h];
  atomicAdd(&vagg[((size_t)dst * VDc + vd) * Hc + h], vv * s1 + s2 * dd);
}

// ---------------- dx = vec_sum*o2 + o3 ----------------
__global__ __launch_bounds__(256) void dx_k(const float* __restrict__ vs,
                                            const float* __restrict__ o,
                                            float* __restrict__ out) {
  int idx = blockIdx.x * 256 + threadIdx.x;
  int row = idx >> 8, col = idx & 255;
  float o2 = o[(size_t)row * 768 + 256 + col];
  float o3 = o[(size_t)row * 768 + 512 + col];
  out[idx] = vs[idx] * o2 + o3;
}

// ---------------- dvec = vec3*o1 + vec_agg ----------------
__global__ __launch_bounds__(256) void dvec_k(const bf16* __restrict__ vp,
                                              const float* __restrict__ o,
                                              const float* __restrict__ vagg,
                                              float* __restrict__ out) {
  size_t idx = (size_t)blockIdx.x * 256 + threadIdx.x;
  int nv = (int)(idx >> 8), h = (int)(idx & 255);
  int n = nv >> 3;
  float v3 = toF(vp[(size_t)nv * 512 + 256 + h]);
  float o1 = o[(size_t)n * 768 + h];
  out[idx] = v3 * o1 + vagg[idx];
}

// ---------------- df = fW * (sum t1*t2 - p1*p2) ----------------
__global__ __launch_bounds__(256) void df_k(
    const bf16* __restrict__ Tt, const bf16* __restrict__ Ts,
    const float* __restrict__ d_ij, const bf16* __restrict__ fW,
    const int* __restrict__ ei, float* __restrict__ out) {
  int e = blockIdx.x, h = threadIdx.x;
  int src = ei[e], dst = ei[Ec + e];
  float S = 0.f, p1 = 0.f, p2 = 0.f;
#pragma unroll
  for (int vd = 0; vd < 8; ++vd) {
    float t1 = toF(Tt[((size_t)dst * 8 + vd) * Hc + h]);
    float t2 = toF(Ts[((size_t)src * 8 + vd) * Hc + h]);
    float dd = d_ij[(size_t)e * 8 + vd];
    S += t1 * t2; p1 += t1 * dd; p2 += t2 * dd;
  }
  out[(size_t)e * Hc + h] = toF(fW[(size_t)e * Hc + h]) * (S - p1 * p2);
}

extern "C" void kernel_launch(void* const* d_in, const int* in_sizes, int n_in,
                              void* d_out, int out_size, void* d_ws, size_t ws_size,
                              hipStream_t stream) {
  const float* x    = (const float*)d_in[0];
  const float* vec  = (const float*)d_in[1];
  const int*   ei   = (const int*)d_in[2];
  const float* r_ij = (const float*)d_in[3];
  const float* f_ij = (const float*)d_in[4];
  const float* d_ij = (const float*)d_in[5];
  const float* ln_w = (const float*)d_in[7];
  const float* ln_b = (const float*)d_in[8];
  const float* Wq   = (const float*)d_in[9];
  const float* Wk   = (const float*)d_in[10];
  const float* Wv   = (const float*)d_in[11];
  const float* Wao  = (const float*)d_in[12];
  const float* Wvec = (const float*)d_in[13];
  const float* Wdv  = (const float*)d_in[14];
  const float* bdv  = (const float*)d_in[15];
  const float* Ws   = (const float*)d_in[16];
  const float* bs   = (const float*)d_in[17];
  const float* Wo   = (const float*)d_in[18];
  const float* bo   = (const float*)d_in[19];
  const float* Wf   = (const float*)d_in[20];
  const float* bf_  = (const float*)d_in[21];
  const float* Wsrc = (const float*)d_in[22];
  const float* Wtrg = (const float*)d_in[23];

  char* p = (char*)d_ws;
  auto alloc = [&](size_t bytes) {
    char* r = p; p += (bytes + 255) & ~(size_t)255; return r;
  };
  bf16*  xn_bf   = (bf16*)alloc((size_t)BNc * Hc * 2);
  float* qb      = (float*)alloc((size_t)BNc * Hc * 4);
  float* kb      = (float*)alloc((size_t)BNc * Hc * 4);
  float* vvb     = (float*)alloc((size_t)BNc * Hc * 4);
  bf16*  attn_bf = (bf16*)alloc((size_t)BNc * Hc * 2);
  float* vbuf    = (float*)alloc((size_t)BNc * Hc * 4);
  float* vsum    = (float*)alloc((size_t)BNc * Hc * 4);
  float* xagg    = (float*)alloc((size_t)BNc * Hc * 4);
  bf16*  xagg_bf = (bf16*)alloc((size_t)BNc * Hc * 2);
  float* obuf    = (float*)alloc((size_t)BNc * 3 * Hc * 4);
  float* vagg    = (float*)alloc((size_t)BNc * VDc * Hc * 4);
  bf16*  f_bf    = (bf16*)alloc((size_t)Ec * Hc * 2);
  bf16*  vec_bf  = (bf16*)alloc((size_t)BNc * VDc * Hc * 2);
  bf16*  dv_bf   = (bf16*)alloc((size_t)Ec * Hc * 2);
  bf16*  vp_bf   = (bf16*)alloc((size_t)BNc * VDc * 2 * Hc * 2);
  bf16*  vj_bf   = (bf16*)alloc((size_t)Ec * Hc * 2);
  bf16*  s12_bf  = (bf16*)alloc((size_t)Ec * 2 * Hc * 2);
  bf16*  fW_bf   = (bf16*)alloc((size_t)Ec * Hc * 2);
  bf16*  Tt_bf   = (bf16*)alloc((size_t)BNc * VDc * Hc * 2);
  bf16*  Ts_bf   = (bf16*)alloc((size_t)BNc * VDc * Hc * 2);
  bf16*  Wq_t    = (bf16*)alloc((size_t)Hc * Hc * 2);
  bf16*  Wk_t    = (bf16*)alloc((size_t)Hc * Hc * 2);
  bf16*  Wv_t    = (bf16*)alloc((size_t)Hc * Hc * 2);
  bf16*  Wao_t   = (bf16*)alloc((size_t)Hc * Hc * 2);
  bf16*  Wdv_t   = (bf16*)alloc((size_t)Hc * Hc * 2);
  bf16*  Wf_t    = (bf16*)alloc((size_t)Hc * Hc * 2);
  bf16*  Wsrc_t  = (bf16*)alloc((size_t)Hc * Hc * 2);
  bf16*  Wtrg_t  = (bf16*)alloc((size_t)Hc * Hc * 2);
  bf16*  Wvec_t  = (bf16*)alloc((size_t)2 * Hc * Hc * 2);
  bf16*  Ws_t    = (bf16*)alloc((size_t)2 * Hc * Hc * 2);
  bf16*  Wo_t    = (bf16*)alloc((size_t)3 * Hc * Hc * 2);

  float* out_dx   = (float*)d_out;
  float* out_dvec = (float*)d_out + 524288;
  float* out_df   = (float*)d_out + 4718592;

  hipMemsetAsync(xagg, 0, (size_t)BNc * Hc * 4, stream);
  hipMemsetAsync(vagg, 0, (size_t)BNc * VDc * Hc * 4, stream);

  // weight prep (transpose + cvt)
  wprep_k<<<dim3(8, 8), 256, 0, stream>>>(Wq, Wq_t, Hc, Hc);
  wprep_k<<<dim3(8, 8), 256, 0, stream>>>(Wk, Wk_t, Hc, Hc);
  wprep_k<<<dim3(8, 8), 256, 0, stream>>>(Wv, Wv_t, Hc, Hc);
  wprep_k<<<dim3(8, 8), 256, 0, stream>>>(Wao, Wao_t, Hc, Hc);
  wprep_k<<<dim3(8, 8), 256, 0, stream>>>(Wdv, Wdv_t, Hc, Hc);
  wprep_k<<<dim3(8, 8), 256, 0, stream>>>(Wf, Wf_t, Hc, Hc);
  wprep_k<<<dim3(8, 8), 256, 0, stream>>>(Wsrc, Wsrc_t, Hc, Hc);
  wprep_k<<<dim3(8, 8), 256, 0, stream>>>(Wtrg, Wtrg_t, Hc, Hc);
  wprep_k<<<dim3(8, 16), 256, 0, stream>>>(Wvec, Wvec_t, Hc, 2 * Hc);
  wprep_k<<<dim3(8, 16), 256, 0, stream>>>(Ws, Ws_t, Hc, 2 * Hc);
  wprep_k<<<dim3(8, 24), 256, 0, stream>>>(Wo, Wo_t, Hc, 3 * Hc);

  // input conversions
  cvt_k<<<Ec * Hc / 1024, 256, 0, stream>>>(f_ij, f_bf, Ec * Hc);
  cvt_k<<<BNc * VDc * Hc / 1024, 256, 0, stream>>>(vec, vec_bf, BNc * VDc * Hc);

  // 1. LayerNorm -> bf16
  ln_k<<<BNc, 256, 0, stream>>>(x, ln_w, ln_b, xn_bf);

  // 2. q/k/v projections (MFMA)
  mgemm_k<0, float><<<dim3(16, 2), 256, 0, stream>>>(xn_bf, Wq_t, nullptr, qb, BNc, Hc, Hc);
  mgemm_k<0, float><<<dim3(16, 2), 256, 0, stream>>>(xn_bf, Wk_t, nullptr, kb, BNc, Hc, Hc);
  mgemm_k<0, float><<<dim3(16, 2), 256, 0, stream>>>(xn_bf, Wv_t, nullptr, vvb, BNc, Hc, Hc);

  // 3. attention
  attn_k<<<Bc * NHc, 256, 0, stream>>>(qb, kb, vvb, attn_bf);

  // 4. v = attn @ Wao
  mgemm_k<0, float><<<dim3(16, 2), 256, 0, stream>>>(attn_bf, Wao_t, nullptr, vbuf, BNc, Hc, Hc);

  // 5. dv = silu(f_ij @ Wdv + bdv)
  mgemm_k<1, bf16><<<dim3(128, 2), 256, 0, stream>>>(f_bf, Wdv_t, bdv, dv_bf, Ec, Hc, Hc);

  // 6. vp = vec @ Wvec ; vec_sum
  mgemm_k<0, bf16><<<dim3(128, 4), 256, 0, stream>>>(vec_bf, Wvec_t, nullptr, vp_bf, BNc * VDc, Hc, 2 * Hc);
  vecsum_k<<<2048, 256, 0, stream>>>(vp_bf, vsum);

  // 7. v_j + x_agg scatter
  vj_k<<<Ec, 256, 0, stream>>>(vbuf, dv_bf, ei, r_ij, vj_bf, xagg);

  // 8. s12 = silu(v_j @ Ws + bs)
  mgemm_k<1, bf16><<<dim3(128, 4), 256, 0, stream>>>(vj_bf, Ws_t, bs, s12_bf, Ec, Hc, 2 * Hc);

  // 9. vec_agg scatter
  scatter_k<<<Ec * VDc, 256, 0, stream>>>(vec, s12_bf, d_ij, ei, vagg);

  // 10. o = x_agg @ Wo + bo
  cvt_k<<<BNc * Hc / 1024, 256, 0, stream>>>(xagg, xagg_bf, BNc * Hc);
  mgemm_k<0, float><<<dim3(16, 6), 256, 0, stream>>>(xagg_bf, Wo_t, bo, obuf, BNc, Hc, 3 * Hc);

  // 11. dx, dvec
  dx_k<<<2048, 256, 0, stream>>>(vsum, obuf, out_dx);
  dvec_k<<<16384, 256, 0, stream>>>(vp_bf, obuf, vagg, out_dvec);

  // 12. df path
  mgemm_k<1, bf16><<<dim3(128, 2), 256, 0, stream>>>(f_bf, Wf_t, bf_, fW_bf, Ec, Hc, Hc);
  mgemm_k<0, bf16><<<dim3(128, 2), 256, 0, stream>>>(vec_bf, Wtrg_t, nullptr, Tt_bf, BNc * VDc, Hc, Hc);
  mgemm_k<0, bf16><<<dim3(128, 2), 256, 0, stream>>>(vec_bf, Wsrc_t, nullptr, Ts_bf, BNc * VDc, Hc, Hc);
  df_k<<<Ec, 256, 0, stream>>>(Tt_bf, Ts_bf, d_ij, fW_bf, ei, out_df);

  (void)in_sizes; (void)n_in; (void)out_size; (void)ws_size;
}

// Round 4
// 414.047 us; speedup vs baseline: 1.8245x; 1.2231x over previous
//
#include <hip/hip_runtime.h>
#include <hip/hip_bf16.h>
#include <math.h>

typedef __hip_bfloat16 bf16;
#define DEV __device__ __forceinline__
DEV float silu_f(float x) { return x / (1.0f + __expf(-x)); }
DEV float toF(bf16 x) { return __bfloat162float(x); }
DEV void storeF(float* p, float v) { *p = v; }
DEV void storeF(bf16* p, float v) { *p = __float2bfloat16(v); }

constexpr int Bc = 8, Nc = 256, BNc = 2048, Ec = 16384;
constexpr int Hc = 256, NHc = 8, HDc = 32, VDc = 8;

typedef __attribute__((ext_vector_type(8))) short short8;
typedef __attribute__((ext_vector_type(4))) float floatx4;

DEV void async_copy16(const void* g, void* l) {
  __builtin_amdgcn_global_load_lds(
      (const __attribute__((address_space(1))) void*)g,
      (__attribute__((address_space(3))) void*)l, 16, 0, 0);
}

// ---------------- CSR build: histogram / scan / fill ----------------
__global__ __launch_bounds__(256) void hist_k(const int* __restrict__ ei,
                                              int* __restrict__ deg) {
  int e = blockIdx.x * 256 + threadIdx.x;
  atomicAdd(&deg[ei[Ec + e]], 1);
}

__global__ __launch_bounds__(256) void scan_k(const int* __restrict__ deg,
                                              int* __restrict__ rowptr) {
  __shared__ int part[256];
  int t = threadIdx.x;
  int loc[8], s = 0;
#pragma unroll
  for (int i = 0; i < 8; ++i) { loc[i] = s; s += deg[t * 8 + i]; }
  part[t] = s; __syncthreads();
  for (int off = 1; off < 256; off <<= 1) {
    int v = (t >= off) ? part[t - off] : 0;
    __syncthreads();
    part[t] += v;
    __syncthreads();
  }
  int base = (t == 0) ? 0 : part[t - 1];
#pragma unroll
  for (int i = 0; i < 8; ++i) rowptr[t * 8 + i] = base + loc[i];
  if (t == 255) rowptr[2048] = base + s;
}

__global__ __launch_bounds__(256) void fill_k(const int* __restrict__ ei,
                                              const int* __restrict__ rowptr,
                                              int* __restrict__ cursor,
                                              int* __restrict__ eids) {
  int e = blockIdx.x * 256 + threadIdx.x;
  int d = ei[Ec + e];
  int p = atomicAdd(&cursor[d], 1);
  eids[rowptr[d] + p] = e;
}

// ---------------- weight prep: out[n*K+k] = bf16(in[k*N+n]) ----------------
__global__ __launch_bounds__(256) void wprep_k(const float* __restrict__ in,
                                               bf16* __restrict__ out,
                                               int K, int N) {
  __shared__ float t[32][33];
  int k0 = blockIdx.x * 32, n0 = blockIdx.y * 32;
  int tx = threadIdx.x & 31, ty = threadIdx.x >> 5;
#pragma unroll
  for (int i = 0; i < 32; i += 8)
    t[ty + i][tx] = in[(size_t)(k0 + ty + i) * N + n0 + tx];
  __syncthreads();
#pragma unroll
  for (int i = 0; i < 32; i += 8)
    out[(size_t)(n0 + ty + i) * K + k0 + tx] = __float2bfloat16(t[tx][ty + i]);
}

// ---------------- fp32 -> bf16 convert ----------------
__global__ __launch_bounds__(256) void cvt_k(const float* __restrict__ in,
                                             bf16* __restrict__ out, int n) {
  int i = (blockIdx.x * 256 + threadIdx.x) * 4;
  float4 v = *(const float4*)&in[i];
  union { bf16 b[4]; uint2 u; } o;
  o.b[0] = __float2bfloat16(v.x); o.b[1] = __float2bfloat16(v.y);
  o.b[2] = __float2bfloat16(v.z); o.b[3] = __float2bfloat16(v.w);
  *(uint2*)&out[i] = o.u;
}

// ---------------- LayerNorm -> bf16 ----------------
__global__ __launch_bounds__(256) void ln_k(const float* __restrict__ x,
    const float* __restrict__ w, const float* __restrict__ b,
    bf16* __restrict__ xn) {
  int row = blockIdx.x, h = threadIdx.x;
  float v = x[(size_t)row * Hc + h];
  __shared__ float sm[256];
  sm[h] = v; __syncthreads();
  for (int s = 128; s > 0; s >>= 1) { if (h < s) sm[h] += sm[h + s]; __syncthreads(); }
  float mu = sm[0] * (1.0f / 256.0f);
  __syncthreads();
  float d = v - mu;
  sm[h] = d * d; __syncthreads();
  for (int s = 128; s > 0; s >>= 1) { if (h < s) sm[h] += sm[h + s]; __syncthreads(); }
  float var = sm[0] * (1.0f / 256.0f);
  float r = rsqrtf(var + 1e-5f);
  xn[(size_t)row * Hc + h] = __float2bfloat16(d * r * w[h] + b[h]);
}

// ---------------- MFMA GEMM: C = act(A @ Bt^T + bias) ----------------
template <int ACT, typename TC>
__global__ __launch_bounds__(256) void mgemm_k(
    const bf16* __restrict__ A, const bf16* __restrict__ Bt,
    const float* __restrict__ bias, TC* __restrict__ C,
    int M, int K, int N) {
  __shared__ bf16 Als[128 * 32];
  __shared__ bf16 Bls[128 * 32];
  int tid = threadIdx.x;
  int lane = tid & 63, w = tid >> 6;
  int m0 = blockIdx.x * 128, n0 = blockIdx.y * 128;
  int wm = (w & 1) * 64, wn = (w >> 1) * 64;
  int fm = lane & 15, g = lane >> 4;
  floatx4 acc[4][4] = {};
  for (int k0 = 0; k0 < K; k0 += 32) {
#pragma unroll
    for (int t = 0; t < 2; ++t) {
      int c = t * 256 + w * 64 + lane;
      int r = c >> 2, q = c & 3;
      bf16* ldsA = &Als[(t * 256 + w * 64) * 8 + lane * 8];
      bf16* ldsB = &Bls[(t * 256 + w * 64) * 8 + lane * 8];
      async_copy16(A + (size_t)(m0 + r) * K + k0 + q * 8, ldsA);
      async_copy16(Bt + (size_t)(n0 + r) * K + k0 + q * 8, ldsB);
    }
    __syncthreads();
    short8 af[4], bg[4];
#pragma unroll
    for (int i = 0; i < 4; ++i) {
      af[i] = *(const short8*)&Als[(wm + i * 16 + fm) * 32 + g * 8];
      bg[i] = *(const short8*)&Bls[(wn + i * 16 + fm) * 32 + g * 8];
    }
#pragma unroll
    for (int mi = 0; mi < 4; ++mi)
#pragma unroll
      for (int ni = 0; ni < 4; ++ni)
        acc[mi][ni] = __builtin_amdgcn_mfma_f32_16x16x32_bf16(
            af[mi], bg[ni], acc[mi][ni], 0, 0, 0);
    __syncthreads();
  }
#pragma unroll
  for (int mi = 0; mi < 4; ++mi) {
    int row0 = m0 + wm + mi * 16 + g * 4;
#pragma unroll
    for (int ni = 0; ni < 4; ++ni) {
      int col = n0 + wn + ni * 16 + fm;
      float bv = bias ? bias[col] : 0.0f;
#pragma unroll
      for (int r = 0; r < 4; ++r) {
        float v = acc[mi][ni][r] + bv;
        if (ACT) v = silu_f(v);
        storeF(&C[(size_t)(row0 + r) * N + col], v);
      }
    }
  }
}

// ---------------- attention per (b,h) ----------------
__global__ __launch_bounds__(256) void attn_k(
    const float* __restrict__ qb, const float* __restrict__ kb,
    const float* __restrict__ vb, bf16* __restrict__ ob) {
  int b = blockIdx.x >> 3, h = blockIdx.x & 7;
  int i = threadIdx.x;
  __shared__ float Ks[256 * 32];
  __shared__ float Vs[256 * 32];
  size_t rowoff = ((size_t)(b * Nc + i)) * Hc + h * HDc;
#pragma unroll
  for (int d4 = 0; d4 < 8; ++d4) {
    *(float4*)&Ks[i * 32 + d4 * 4] = *(const float4*)&kb[rowoff + d4 * 4];
    *(float4*)&Vs[i * 32 + d4 * 4] = *(const float4*)&vb[rowoff + d4 * 4];
  }
  float q[32], acc[32];
#pragma unroll
  for (int d4 = 0; d4 < 8; ++d4)
    *(float4*)&q[d4 * 4] = *(const float4*)&qb[rowoff + d4 * 4];
#pragma unroll
  for (int d = 0; d < 32; ++d) acc[d] = 0.f;
  __syncthreads();
  for (int j = 0; j < 256; ++j) {
    float s = 0.f;
#pragma unroll
    for (int d = 0; d < 32; ++d) s += q[d] * Ks[j * 32 + d];
    s *= 0.17677669529663687f;
    float p = silu_f(s);
#pragma unroll
    for (int d = 0; d < 32; ++d) acc[d] += p * Vs[j * 32 + d];
  }
#pragma unroll
  for (int d = 0; d < 32; ++d)
    ob[rowoff + d] = __float2bfloat16(acc[d] * (1.0f / 256.0f));
}

// ---------------- vec_sum ----------------
__global__ __launch_bounds__(256) void vecsum_k(const bf16* __restrict__ vp,
                                                float* __restrict__ vs) {
  int idx = blockIdx.x * 256 + threadIdx.x;
  int n = idx >> 8, h = idx & 255;
  float s = 0.f;
#pragma unroll
  for (int vd = 0; vd < 8; ++vd) s += toF(vp[((size_t)n * 8 + vd) * 512 + h]);
  vs[idx] = s;
}

// ---------------- v_j = v[src]*cut*dv (no atomics) ----------------
__global__ __launch_bounds__(256) void vj_k(
    const float* __restrict__ v, const bf16* __restrict__ dv,
    const int* __restrict__ ei, const float* __restrict__ r_ij,
    bf16* __restrict__ vj) {
  int e = blockIdx.x, h = threadIdx.x;
  int src = ei[e];
  float r = r_ij[e];
  float cut = (r < 5.0f) ? 0.5f * (cosf(0.6283185307179586f * r) + 1.0f) : 0.0f;
  float val = v[(size_t)src * Hc + h] * cut * toF(dv[(size_t)e * Hc + h]);
  vj[(size_t)e * Hc + h] = __float2bfloat16(val);
}

// ---------------- x_agg via CSR gather -> bf16 ----------------
__global__ __launch_bounds__(256) void xagg_k(const bf16* __restrict__ vj,
                                              const int* __restrict__ rowptr,
                                              const int* __restrict__ eids,
                                              bf16* __restrict__ xagg_bf) {
  int n = blockIdx.x, h = threadIdx.x;
  float acc = 0.f;
  int lo = rowptr[n], hi = rowptr[n + 1];
  for (int i = lo; i < hi; ++i) {
    int e = eids[i];
    acc += toF(vj[(size_t)e * Hc + h]);
  }
  xagg_bf[(size_t)n * Hc + h] = __float2bfloat16(acc);
}

// ---------------- fused vec_agg gather + dvec epilogue ----------------
// out_dvec[n,vd,h] = vp3[n,vd,h]*o1[n,h] + sum_{e in(n)} vec[src,vd,h]*s1[e,h] + s2[e,h]*d[e,vd]
__global__ __launch_bounds__(256) void dvec_agg_k(
    const bf16* __restrict__ vec_bf, const bf16* __restrict__ s12,
    const float* __restrict__ d_ij, const int* __restrict__ ei,
    const int* __restrict__ rowptr, const int* __restrict__ eids,
    const bf16* __restrict__ vp, const float* __restrict__ o,
    float* __restrict__ out) {
  int n = blockIdx.x, h = threadIdx.x;
  float acc[8] = {};
  int lo = rowptr[n], hi = rowptr[n + 1];
  for (int i = lo; i < hi; ++i) {
    int e = eids[i];
    int src = ei[e];
    float s1 = toF(s12[(size_t)e * 512 + h]);
    float s2 = toF(s12[(size_t)e * 512 + 256 + h]);
#pragma unroll
    for (int vd = 0; vd < 8; ++vd) {
      float dd = d_ij[(size_t)e * VDc + vd];
      acc[vd] += toF(vec_bf[((size_t)src * VDc + vd) * Hc + h]) * s1 + s2 * dd;
    }
  }
  float o1 = o[(size_t)n * 768 + h];
#pragma unroll
  for (int vd = 0; vd < 8; ++vd) {
    float v3 = toF(vp[((size_t)n * VDc + vd) * 512 + 256 + h]);
    out[((size_t)n * VDc + vd) * Hc + h] = v3 * o1 + acc[vd];
  }
}

// ---------------- dx = vec_sum*o2 + o3 ----------------
__global__ __launch_bounds__(256) void dx_k(const float* __restrict__ vs,
                                            const float* __restrict__ o,
                                            float* __restrict__ out) {
  int idx = blockIdx.x * 256 + threadIdx.x;
  int row = idx >> 8, col = idx & 255;
  float o2 = o[(size_t)row * 768 + 256 + col];
  float o3 = o[(size_t)row * 768 + 512 + col];
  out[idx] = vs[idx] * o2 + o3;
}

// ---------------- df = fW * (sum t1*t2 - p1*p2) ----------------
__global__ __launch_bounds__(256) void df_k(
    const bf16* __restrict__ Tt, const bf16* __restrict__ Ts,
    const float* __restrict__ d_ij, const bf16* __restrict__ fW,
    const int* __restrict__ ei, float* __restrict__ out) {
  int e = blockIdx.x, h = threadIdx.x;
  int src = ei[e], dst = ei[Ec + e];
  float S = 0.f, p1 = 0.f, p2 = 0.f;
#pragma unroll
  for (int vd = 0; vd < 8; ++vd) {
    float t1 = toF(Tt[((size_t)dst * 8 + vd) * Hc + h]);
    float t2 = toF(Ts[((size_t)src * 8 + vd) * Hc + h]);
    float dd = d_ij[(size_t)e * 8 + vd];
    S += t1 * t2; p1 += t1 * dd; p2 += t2 * dd;
  }
  out[(size_t)e * Hc + h] = toF(fW[(size_t)e * Hc + h]) * (S - p1 * p2);
}

extern "C" void kernel_launch(void* const* d_in, const int* in_sizes, int n_in,
                              void* d_out, int out_size, void* d_ws, size_t ws_size,
                              hipStream_t stream) {
  const float* x    = (const float*)d_in[0];
  const float* vec  = (const float*)d_in[1];
  const int*   ei   = (const int*)d_in[2];
  const float* r_ij = (const float*)d_in[3];
  const float* f_ij = (const float*)d_in[4];
  const float* d_ij = (const float*)d_in[5];
  const float* ln_w = (const float*)d_in[7];
  const float* ln_b = (const float*)d_in[8];
  const float* Wq   = (const float*)d_in[9];
  const float* Wk   = (const float*)d_in[10];
  const float* Wv   = (const float*)d_in[11];
  const float* Wao  = (const float*)d_in[12];
  const float* Wvec = (const float*)d_in[13];
  const float* Wdv  = (const float*)d_in[14];
  const float* bdv  = (const float*)d_in[15];
  const float* Ws   = (const float*)d_in[16];
  const float* bs   = (const float*)d_in[17];
  const float* Wo   = (const float*)d_in[18];
  const float* bo   = (const float*)d_in[19];
  const float* Wf   = (const float*)d_in[20];
  const float* bf_  = (const float*)d_in[21];
  const float* Wsrc = (const float*)d_in[22];
  const float* Wtrg = (const float*)d_in[23];

  char* p = (char*)d_ws;
  auto alloc = [&](size_t bytes) {
    char* r = p; p += (bytes + 255) & ~(size_t)255; return r;
  };
  bf16*  xn_bf   = (bf16*)alloc((size_t)BNc * Hc * 2);
  float* qb      = (float*)alloc((size_t)BNc * Hc * 4);
  float* kb      = (float*)alloc((size_t)BNc * Hc * 4);
  float* vvb     = (float*)alloc((size_t)BNc * Hc * 4);
  bf16*  attn_bf = (bf16*)alloc((size_t)BNc * Hc * 2);
  float* vbuf    = (float*)alloc((size_t)BNc * Hc * 4);
  float* vsum    = (float*)alloc((size_t)BNc * Hc * 4);
  bf16*  xagg_bf = (bf16*)alloc((size_t)BNc * Hc * 2);
  float* obuf    = (float*)alloc((size_t)BNc * 3 * Hc * 4);
  bf16*  f_bf    = (bf16*)alloc((size_t)Ec * Hc * 2);
  bf16*  vec_bf  = (bf16*)alloc((size_t)BNc * VDc * Hc * 2);
  bf16*  dv_bf   = (bf16*)alloc((size_t)Ec * Hc * 2);
  bf16*  vp_bf   = (bf16*)alloc((size_t)BNc * VDc * 2 * Hc * 2);
  bf16*  vj_bf   = (bf16*)alloc((size_t)Ec * Hc * 2);
  bf16*  s12_bf  = (bf16*)alloc((size_t)Ec * 2 * Hc * 2);
  bf16*  fW_bf   = (bf16*)alloc((size_t)Ec * Hc * 2);
  bf16*  Tt_bf   = (bf16*)alloc((size_t)BNc * VDc * Hc * 2);
  bf16*  Ts_bf   = (bf16*)alloc((size_t)BNc * VDc * Hc * 2);
  bf16*  Wq_t    = (bf16*)alloc((size_t)Hc * Hc * 2);
  bf16*  Wk_t    = (bf16*)alloc((size_t)Hc * Hc * 2);
  bf16*  Wv_t    = (bf16*)alloc((size_t)Hc * Hc * 2);
  bf16*  Wao_t   = (bf16*)alloc((size_t)Hc * Hc * 2);
  bf16*  Wdv_t   = (bf16*)alloc((size_t)Hc * Hc * 2);
  bf16*  Wf_t    = (bf16*)alloc((size_t)Hc * Hc * 2);
  bf16*  Wsrc_t  = (bf16*)alloc((size_t)Hc * Hc * 2);
  bf16*  Wtrg_t  = (bf16*)alloc((size_t)Hc * Hc * 2);
  bf16*  Wvec_t  = (bf16*)alloc((size_t)2 * Hc * Hc * 2);
  bf16*  Ws_t    = (bf16*)alloc((size_t)2 * Hc * Hc * 2);
  bf16*  Wo_t    = (bf16*)alloc((size_t)3 * Hc * Hc * 2);
  int*   deg     = (int*)alloc(2048 * 4);
  int*   cursor  = (int*)alloc(2048 * 4);
  int*   rowptr  = (int*)alloc(2049 * 4);
  int*   eids    = (int*)alloc(Ec * 4);

  float* out_dx   = (float*)d_out;
  float* out_dvec = (float*)d_out + 524288;
  float* out_df   = (float*)d_out + 4718592;

  // CSR build
  hipMemsetAsync(deg, 0, 2048 * 4, stream);
  hipMemsetAsync(cursor, 0, 2048 * 4, stream);
  hist_k<<<Ec / 256, 256, 0, stream>>>(ei, deg);
  scan_k<<<1, 256, 0, stream>>>(deg, rowptr);
  fill_k<<<Ec / 256, 256, 0, stream>>>(ei, rowptr, cursor, eids);

  // weight prep (transpose + cvt)
  wprep_k<<<dim3(8, 8), 256, 0, stream>>>(Wq, Wq_t, Hc, Hc);
  wprep_k<<<dim3(8, 8), 256, 0, stream>>>(Wk, Wk_t, Hc, Hc);
  wprep_k<<<dim3(8, 8), 256, 0, stream>>>(Wv, Wv_t, Hc, Hc);
  wprep_k<<<dim3(8, 8), 256, 0, stream>>>(Wao, Wao_t, Hc, Hc);
  wprep_k<<<dim3(8, 8), 256, 0, stream>>>(Wdv, Wdv_t, Hc, Hc);
  wprep_k<<<dim3(8, 8), 256, 0, stream>>>(Wf, Wf_t, Hc, Hc);
  wprep_k<<<dim3(8, 8), 256, 0, stream>>>(Wsrc, Wsrc_t, Hc, Hc);
  wprep_k<<<dim3(8, 8), 256, 0, stream>>>(Wtrg, Wtrg_t, Hc, Hc);
  wprep_k<<<dim3(8, 16), 256, 0, stream>>>(Wvec, Wvec_t, Hc, 2 * Hc);
  wprep_k<<<dim3(8, 16), 256, 0, stream>>>(Ws, Ws_t, Hc, 2 * Hc);
  wprep_k<<<dim3(8, 24), 256, 0, stream>>>(Wo, Wo_t, Hc, 3 * Hc);

  // input conversions
  cvt_k<<<Ec * Hc / 1024, 256, 0, stream>>>(f_ij, f_bf, Ec * Hc);
  cvt_k<<<BNc * VDc * Hc / 1024, 256, 0, stream>>>(vec, vec_bf, BNc * VDc * Hc);

  // 1. LayerNorm -> bf16
  ln_k<<<BNc, 256, 0, stream>>>(x, ln_w, ln_b, xn_bf);

  // 2. q/k/v projections (MFMA)
  mgemm_k<0, float><<<dim3(16, 2), 256, 0, stream>>>(xn_bf, Wq_t, nullptr, qb, BNc, Hc, Hc);
  mgemm_k<0, float><<<dim3(16, 2), 256, 0, stream>>>(xn_bf, Wk_t, nullptr, kb, BNc, Hc, Hc);
  mgemm_k<0, float><<<dim3(16, 2), 256, 0, stream>>>(xn_bf, Wv_t, nullptr, vvb, BNc, Hc, Hc);

  // 3. attention
  attn_k<<<Bc * NHc, 256, 0, stream>>>(qb, kb, vvb, attn_bf);

  // 4. v = attn @ Wao
  mgemm_k<0, float><<<dim3(16, 2), 256, 0, stream>>>(attn_bf, Wao_t, nullptr, vbuf, BNc, Hc, Hc);

  // 5. dv = silu(f_ij @ Wdv + bdv)
  mgemm_k<1, bf16><<<dim3(128, 2), 256, 0, stream>>>(f_bf, Wdv_t, bdv, dv_bf, Ec, Hc, Hc);

  // 6. vp = vec @ Wvec ; vec_sum
  mgemm_k<0, bf16><<<dim3(128, 4), 256, 0, stream>>>(vec_bf, Wvec_t, nullptr, vp_bf, BNc * VDc, Hc, 2 * Hc);
  vecsum_k<<<2048, 256, 0, stream>>>(vp_bf, vsum);

  // 7. v_j (no atomics)
  vj_k<<<Ec, 256, 0, stream>>>(vbuf, dv_bf, ei, r_ij, vj_bf);

  // 8. x_agg via CSR gather
  xagg_k<<<BNc, 256, 0, stream>>>(vj_bf, rowptr, eids, xagg_bf);

  // 9. s12 = silu(v_j @ Ws + bs)
  mgemm_k<1, bf16><<<dim3(128, 4), 256, 0, stream>>>(vj_bf, Ws_t, bs, s12_bf, Ec, Hc, 2 * Hc);

  // 10. o = x_agg @ Wo + bo
  mgemm_k<0, float><<<dim3(16, 6), 256, 0, stream>>>(xagg_bf, Wo_t, bo, obuf, BNc, Hc, 3 * Hc);

  // 11. dx
  dx_k<<<2048, 256, 0, stream>>>(vsum, obuf, out_dx);

  // 12. fused vec_agg + dvec epilogue
  dvec_agg_k<<<BNc, 256, 0, stream>>>(vec_bf, s12_bf, d_ij, ei, rowptr, eids,
                                      vp_bf, obuf, out_dvec);

  // 13. df path
  mgemm_k<1, bf16><<<dim3(128, 2), 256, 0, stream>>>(f_bf, Wf_t, bf_, fW_bf, Ec, Hc, Hc);
  mgemm_k<0, bf16><<<dim3(128, 2), 256, 0, stream>>>(vec_bf, Wtrg_t, nullptr, Tt_bf, BNc * VDc, Hc, Hc);
  mgemm_k<0, bf16><<<dim3(128, 2), 256, 0, stream>>>(vec_bf, Wsrc_t, nullptr, Ts_bf, BNc * VDc, Hc, Hc);
  df_k<<<Ec, 256, 0, stream>>>(Tt_bf, Ts_bf, d_ij, fW_bf, ei, out_df);

  (void)in_sizes; (void)n_in; (void)out_size; (void)ws_size;
}

// Round 5
// 354.641 us; speedup vs baseline: 2.1302x; 1.1675x over previous
//
#include <hip/hip_runtime.h>
#include <hip/hip_bf16.h>
#include <math.h>

typedef __hip_bfloat16 bf16;
#define DEV __device__ __forceinline__
DEV float silu_f(float x) { return x / (1.0f + __expf(-x)); }
DEV float toF(bf16 x) { return __bfloat162float(x); }
DEV void storeF(float* p, float v) { *p = v; }
DEV void storeF(bf16* p, float v) { *p = __float2bfloat16(v); }

constexpr int Bc = 8, Nc = 256, BNc = 2048, Ec = 16384;
constexpr int Hc = 256, NHc = 8, HDc = 32, VDc = 8;

typedef __attribute__((ext_vector_type(8))) short short8;
typedef __attribute__((ext_vector_type(4))) float floatx4;

DEV void async_copy16(const void* g, void* l) {
  __builtin_amdgcn_global_load_lds(
      (const __attribute__((address_space(1))) void*)g,
      (__attribute__((address_space(3))) void*)l, 16, 0, 0);
}

// ---------------- CSR build: histogram / scan / fill ----------------
__global__ __launch_bounds__(256) void hist_k(const int* __restrict__ ei,
                                              int* __restrict__ deg) {
  int e = blockIdx.x * 256 + threadIdx.x;
  atomicAdd(&deg[ei[Ec + e]], 1);
}

__global__ __launch_bounds__(256) void scan_k(const int* __restrict__ deg,
                                              int* __restrict__ rowptr) {
  __shared__ int part[256];
  int t = threadIdx.x;
  int loc[8], s = 0;
#pragma unroll
  for (int i = 0; i < 8; ++i) { loc[i] = s; s += deg[t * 8 + i]; }
  part[t] = s; __syncthreads();
  for (int off = 1; off < 256; off <<= 1) {
    int v = (t >= off) ? part[t - off] : 0;
    __syncthreads();
    part[t] += v;
    __syncthreads();
  }
  int base = (t == 0) ? 0 : part[t - 1];
#pragma unroll
  for (int i = 0; i < 8; ++i) rowptr[t * 8 + i] = base + loc[i];
  if (t == 255) rowptr[2048] = base + s;
}

__global__ __launch_bounds__(256) void fill_k(const int* __restrict__ ei,
                                              const int* __restrict__ rowptr,
                                              int* __restrict__ cursor,
                                              int* __restrict__ eids) {
  int e = blockIdx.x * 256 + threadIdx.x;
  int d = ei[Ec + e];
  int p = atomicAdd(&cursor[d], 1);
  eids[rowptr[d] + p] = e;
}

// ---------------- weight prep: out[n*K+k] = bf16(in[k*N+n]) ----------------
__global__ __launch_bounds__(256) void wprep_k(const float* __restrict__ in,
                                               bf16* __restrict__ out,
                                               int K, int N) {
  __shared__ float t[32][33];
  int k0 = blockIdx.x * 32, n0 = blockIdx.y * 32;
  int tx = threadIdx.x & 31, ty = threadIdx.x >> 5;
#pragma unroll
  for (int i = 0; i < 32; i += 8)
    t[ty + i][tx] = in[(size_t)(k0 + ty + i) * N + n0 + tx];
  __syncthreads();
#pragma unroll
  for (int i = 0; i < 32; i += 8)
    out[(size_t)(n0 + ty + i) * K + k0 + tx] = __float2bfloat16(t[tx][ty + i]);
}

// ---------------- fp32 -> bf16 convert ----------------
__global__ __launch_bounds__(256) void cvt_k(const float* __restrict__ in,
                                             bf16* __restrict__ out, int n) {
  int i = (blockIdx.x * 256 + threadIdx.x) * 4;
  float4 v = *(const float4*)&in[i];
  union { bf16 b[4]; uint2 u; } o;
  o.b[0] = __float2bfloat16(v.x); o.b[1] = __float2bfloat16(v.y);
  o.b[2] = __float2bfloat16(v.z); o.b[3] = __float2bfloat16(v.w);
  *(uint2*)&out[i] = o.u;
}

// ---------------- LayerNorm -> bf16 ----------------
__global__ __launch_bounds__(256) void ln_k(const float* __restrict__ x,
    const float* __restrict__ w, const float* __restrict__ b,
    bf16* __restrict__ xn) {
  int row = blockIdx.x, h = threadIdx.x;
  float v = x[(size_t)row * Hc + h];
  __shared__ float sm[256];
  sm[h] = v; __syncthreads();
  for (int s = 128; s > 0; s >>= 1) { if (h < s) sm[h] += sm[h + s]; __syncthreads(); }
  float mu = sm[0] * (1.0f / 256.0f);
  __syncthreads();
  float d = v - mu;
  sm[h] = d * d; __syncthreads();
  for (int s = 128; s > 0; s >>= 1) { if (h < s) sm[h] += sm[h + s]; __syncthreads(); }
  float var = sm[0] * (1.0f / 256.0f);
  float r = rsqrtf(var + 1e-5f);
  xn[(size_t)row * Hc + h] = __float2bfloat16(d * r * w[h] + b[h]);
}

// ---------------- MFMA GEMM: C = act(A @ Bt^T + bias) ----------------
template <int ACT, typename TC>
__global__ __launch_bounds__(256) void mgemm_k(
    const bf16* __restrict__ A, const bf16* __restrict__ Bt,
    const float* __restrict__ bias, TC* __restrict__ C,
    int M, int K, int N) {
  __shared__ bf16 Als[128 * 32];
  __shared__ bf16 Bls[128 * 32];
  int tid = threadIdx.x;
  int lane = tid & 63, w = tid >> 6;
  int m0 = blockIdx.x * 128, n0 = blockIdx.y * 128;
  int wm = (w & 1) * 64, wn = (w >> 1) * 64;
  int fm = lane & 15, g = lane >> 4;
  floatx4 acc[4][4] = {};
  for (int k0 = 0; k0 < K; k0 += 32) {
#pragma unroll
    for (int t = 0; t < 2; ++t) {
      int c = t * 256 + w * 64 + lane;
      int r = c >> 2, q = c & 3;
      bf16* ldsA = &Als[(t * 256 + w * 64) * 8 + lane * 8];
      bf16* ldsB = &Bls[(t * 256 + w * 64) * 8 + lane * 8];
      async_copy16(A + (size_t)(m0 + r) * K + k0 + q * 8, ldsA);
      async_copy16(Bt + (size_t)(n0 + r) * K + k0 + q * 8, ldsB);
    }
    __syncthreads();
    short8 af[4], bg[4];
#pragma unroll
    for (int i = 0; i < 4; ++i) {
      af[i] = *(const short8*)&Als[(wm + i * 16 + fm) * 32 + g * 8];
      bg[i] = *(const short8*)&Bls[(wn + i * 16 + fm) * 32 + g * 8];
    }
#pragma unroll
    for (int mi = 0; mi < 4; ++mi)
#pragma unroll
      for (int ni = 0; ni < 4; ++ni)
        acc[mi][ni] = __builtin_amdgcn_mfma_f32_16x16x32_bf16(
            af[mi], bg[ni], acc[mi][ni], 0, 0, 0);
    __syncthreads();
  }
#pragma unroll
  for (int mi = 0; mi < 4; ++mi) {
    int row0 = m0 + wm + mi * 16 + g * 4;
#pragma unroll
    for (int ni = 0; ni < 4; ++ni) {
      int col = n0 + wn + ni * 16 + fm;
      float bv = bias ? bias[col] : 0.0f;
#pragma unroll
      for (int r = 0; r < 4; ++r) {
        float v = acc[mi][ni][r] + bv;
        if (ACT) v = silu_f(v);
        storeF(&C[(size_t)(row0 + r) * N + col], v);
      }
    }
  }
}

// ---------------- MFMA attention per (b,h) ----------------
// qkv: [2048][768] bf16 (q|k|v per row). out: [2048][256] bf16.
// Block = 4 waves; wave w owns Q-rows w*64..w*64+63.
__global__ __launch_bounds__(256) void attn_mfma_k(
    const bf16* __restrict__ qkv, bf16* __restrict__ ob) {
  constexpr int QS = 768;
  int b = blockIdx.x >> 3, h = blockIdx.x & 7;
  int tid = threadIdx.x, lane = tid & 63, w = tid >> 6;
  int fm = lane & 15, g = lane >> 4;
  __shared__ bf16 Vt[32][264];     // V^T, padded
  __shared__ bf16 Ps[4][64][72];   // per-wave P tile, 16B-aligned rows
  const bf16* qb = qkv + (size_t)b * 256 * QS + h * 32;
  const bf16* kb = qb + 256;
  const bf16* vb = qb + 512;
  // stage V^T
#pragma unroll
  for (int c = 0; c < 4; ++c) {
    int chunk = c * 256 + tid;
    int j = chunk >> 2, part = chunk & 3;
    union { short8 v; bf16 x[8]; } t;
    t.v = *(const short8*)(vb + (size_t)j * QS + part * 8);
#pragma unroll
    for (int i = 0; i < 8; ++i) Vt[part * 8 + i][j] = t.x[i];
  }
  __syncthreads();
  // Q fragments (A-layout: lane = row fm, k-chunk g*8)
  short8 af[4];
#pragma unroll
  for (int mi = 0; mi < 4; ++mi)
    af[mi] = *(const short8*)(qb + (size_t)(w * 64 + mi * 16 + fm) * QS + g * 8);
  floatx4 oacc[4][2] = {};
  for (int jt = 0; jt < 4; ++jt) {
    // S tile (64 x 64) -> silu -> Ps
#pragma unroll
    for (int ni = 0; ni < 4; ++ni) {
      short8 bg = *(const short8*)(kb + (size_t)(jt * 64 + ni * 16 + fm) * QS + g * 8);
#pragma unroll
      for (int mi = 0; mi < 4; ++mi) {
        floatx4 z = {0.f, 0.f, 0.f, 0.f};
        floatx4 s = __builtin_amdgcn_mfma_f32_16x16x32_bf16(af[mi], bg, z, 0, 0, 0);
#pragma unroll
        for (int r = 0; r < 4; ++r) {
          float v = silu_f(s[r] * 0.17677669529663687f);
          Ps[w][mi * 16 + g * 4 + r][ni * 16 + fm] = __float2bfloat16(v);
        }
      }
    }
    // PV accumulate (wave-private Ps; DS in-order, no barrier needed)
#pragma unroll
    for (int kt = 0; kt < 2; ++kt) {
      short8 bv0 = *(const short8*)&Vt[fm][jt * 64 + kt * 32 + g * 8];
      short8 bv1 = *(const short8*)&Vt[16 + fm][jt * 64 + kt * 32 + g * 8];
#pragma unroll
      for (int mi = 0; mi < 4; ++mi) {
        short8 ap = *(const short8*)&Ps[w][mi * 16 + fm][kt * 32 + g * 8];
        oacc[mi][0] = __builtin_amdgcn_mfma_f32_16x16x32_bf16(ap, bv0, oacc[mi][0], 0, 0, 0);
        oacc[mi][1] = __builtin_amdgcn_mfma_f32_16x16x32_bf16(ap, bv1, oacc[mi][1], 0, 0, 0);
      }
    }
  }
#pragma unroll
  for (int mi = 0; mi < 4; ++mi)
#pragma unroll
    for (int ni = 0; ni < 2; ++ni)
#pragma unroll
      for (int r = 0; r < 4; ++r) {
        int row = w * 64 + mi * 16 + g * 4 + r;
        int d = ni * 16 + fm;
        ob[((size_t)(b * 256 + row)) * 256 + h * 32 + d] =
            __float2bfloat16(oacc[mi][ni][r] * (1.0f / 256.0f));
      }
}

// ---------------- vec_sum ----------------
__global__ __launch_bounds__(256) void vecsum_k(const bf16* __restrict__ vp,
                                                float* __restrict__ vs) {
  int idx = blockIdx.x * 256 + threadIdx.x;
  int n = idx >> 8, h = idx & 255;
  float s = 0.f;
#pragma unroll
  for (int vd = 0; vd < 8; ++vd) s += toF(vp[((size_t)n * 8 + vd) * 512 + h]);
  vs[idx] = s;
}

// ---------------- v_j = v[src]*cut*dv ----------------
__global__ __launch_bounds__(256) void vj_k(
    const float* __restrict__ v, const bf16* __restrict__ dv,
    const int* __restrict__ ei, const float* __restrict__ r_ij,
    bf16* __restrict__ vj) {
  int e = blockIdx.x, h = threadIdx.x;
  int src = ei[e];
  float r = r_ij[e];
  float cut = (r < 5.0f) ? 0.5f * (cosf(0.6283185307179586f * r) + 1.0f) : 0.0f;
  float val = v[(size_t)src * Hc + h] * cut * toF(dv[(size_t)e * Hc + h]);
  vj[(size_t)e * Hc + h] = __float2bfloat16(val);
}

// ---------------- x_agg via CSR gather -> bf16 ----------------
__global__ __launch_bounds__(256) void xagg_k(const bf16* __restrict__ vj,
                                              const int* __restrict__ rowptr,
                                              const int* __restrict__ eids,
                                              bf16* __restrict__ xagg_bf) {
  int n = blockIdx.x, h = threadIdx.x;
  float acc = 0.f;
  int lo = rowptr[n], hi = rowptr[n + 1];
  for (int i = lo; i < hi; ++i) {
    int e = eids[i];
    acc += toF(vj[(size_t)e * Hc + h]);
  }
  xagg_bf[(size_t)n * Hc + h] = __float2bfloat16(acc);
}

// ---------------- fused vec_agg gather + dvec epilogue ----------------
__global__ __launch_bounds__(256) void dvec_agg_k(
    const bf16* __restrict__ vec_bf, const bf16* __restrict__ s12,
    const float* __restrict__ d_ij, const int* __restrict__ ei,
    const int* __restrict__ rowptr, const int* __restrict__ eids,
    const bf16* __restrict__ vp, const float* __restrict__ o,
    float* __restrict__ out) {
  int n = blockIdx.x, h = threadIdx.x;
  float acc[8] = {};
  int lo = rowptr[n], hi = rowptr[n + 1];
  for (int i = lo; i < hi; ++i) {
    int e = eids[i];
    int src = ei[e];
    float s1 = toF(s12[(size_t)e * 512 + h]);
    float s2 = toF(s12[(size_t)e * 512 + 256 + h]);
#pragma unroll
    for (int vd = 0; vd < 8; ++vd) {
      float dd = d_ij[(size_t)e * VDc + vd];
      acc[vd] += toF(vec_bf[((size_t)src * VDc + vd) * Hc + h]) * s1 + s2 * dd;
    }
  }
  float o1 = o[(size_t)n * 768 + h];
#pragma unroll
  for (int vd = 0; vd < 8; ++vd) {
    float v3 = toF(vp[((size_t)n * VDc + vd) * 512 + 256 + h]);
    out[((size_t)n * VDc + vd) * Hc + h] = v3 * o1 + acc[vd];
  }
}

// ---------------- dx = vec_sum*o2 + o3 ----------------
__global__ __launch_bounds__(256) void dx_k(const float* __restrict__ vs,
                                            const float* __restrict__ o,
                                            float* __restrict__ out) {
  int idx = blockIdx.x * 256 + threadIdx.x;
  int row = idx >> 8, col = idx & 255;
  float o2 = o[(size_t)row * 768 + 256 + col];
  float o3 = o[(size_t)row * 768 + 512 + col];
  out[idx] = vs[idx] * o2 + o3;
}

// ---------------- df = fW * (sum t1*t2 - p1*p2) ----------------
// T: [16384][512] = Ttrg | Tsrc interleaved per row.
__global__ __launch_bounds__(256) void df_k(
    const bf16* __restrict__ T, const float* __restrict__ d_ij,
    const bf16* __restrict__ fW, const int* __restrict__ ei,
    float* __restrict__ out) {
  int e = blockIdx.x, h = threadIdx.x;
  int src = ei[e], dst = ei[Ec + e];
  float S = 0.f, p1 = 0.f, p2 = 0.f;
#pragma unroll
  for (int vd = 0; vd < 8; ++vd) {
    float t1 = toF(T[((size_t)dst * 8 + vd) * 512 + h]);
    float t2 = toF(T[((size_t)src * 8 + vd) * 512 + 256 + h]);
    float dd = d_ij[(size_t)e * 8 + vd];
    S += t1 * t2; p1 += t1 * dd; p2 += t2 * dd;
  }
  out[(size_t)e * Hc + h] = toF(fW[(size_t)e * Hc + h]) * (S - p1 * p2);
}

extern "C" void kernel_launch(void* const* d_in, const int* in_sizes, int n_in,
                              void* d_out, int out_size, void* d_ws, size_t ws_size,
                              hipStream_t stream) {
  const float* x    = (const float*)d_in[0];
  const float* vec  = (const float*)d_in[1];
  const int*   ei   = (const int*)d_in[2];
  const float* r_ij = (const float*)d_in[3];
  const float* f_ij = (const float*)d_in[4];
  const float* d_ij = (const float*)d_in[5];
  const float* ln_w = (const float*)d_in[7];
  const float* ln_b = (const float*)d_in[8];
  const float* Wq   = (const float*)d_in[9];
  const float* Wk   = (const float*)d_in[10];
  const float* Wv   = (const float*)d_in[11];
  const float* Wao  = (const float*)d_in[12];
  const float* Wvec = (const float*)d_in[13];
  const float* Wdv  = (const float*)d_in[14];
  const float* bdv  = (const float*)d_in[15];
  const float* Ws   = (const float*)d_in[16];
  const float* bs   = (const float*)d_in[17];
  const float* Wo   = (const float*)d_in[18];
  const float* bo   = (const float*)d_in[19];
  const float* Wf   = (const float*)d_in[20];
  const float* bf_  = (const float*)d_in[21];
  const float* Wsrc = (const float*)d_in[22];
  const float* Wtrg = (const float*)d_in[23];

  char* p = (char*)d_ws;
  auto alloc = [&](size_t bytes) {
    char* r = p; p += (bytes + 255) & ~(size_t)255; return r;
  };
  bf16*  xn_bf   = (bf16*)alloc((size_t)BNc * Hc * 2);
  bf16*  qkv_bf  = (bf16*)alloc((size_t)BNc * 3 * Hc * 2);   // [2048][768]
  bf16*  attn_bf = (bf16*)alloc((size_t)BNc * Hc * 2);
  float* vbuf    = (float*)alloc((size_t)BNc * Hc * 4);
  float* vsum    = (float*)alloc((size_t)BNc * Hc * 4);
  bf16*  xagg_bf = (bf16*)alloc((size_t)BNc * Hc * 2);
  float* obuf    = (float*)alloc((size_t)BNc * 3 * Hc * 4);
  bf16*  f_bf    = (bf16*)alloc((size_t)Ec * Hc * 2);
  bf16*  vec_bf  = (bf16*)alloc((size_t)BNc * VDc * Hc * 2);
  bf16*  dv_bf   = (bf16*)alloc((size_t)Ec * Hc * 2);
  bf16*  vp_bf   = (bf16*)alloc((size_t)BNc * VDc * 2 * Hc * 2);
  bf16*  vj_bf   = (bf16*)alloc((size_t)Ec * Hc * 2);
  bf16*  s12_bf  = (bf16*)alloc((size_t)Ec * 2 * Hc * 2);
  bf16*  fW_bf   = (bf16*)alloc((size_t)Ec * Hc * 2);
  bf16*  T_bf    = (bf16*)alloc((size_t)BNc * VDc * 2 * Hc * 2); // [16384][512] trg|src
  bf16*  Wqkv_t  = (bf16*)alloc((size_t)3 * Hc * Hc * 2);
  bf16*  Wao_t   = (bf16*)alloc((size_t)Hc * Hc * 2);
  bf16*  Wdv_t   = (bf16*)alloc((size_t)Hc * Hc * 2);
  bf16*  Wf_t    = (bf16*)alloc((size_t)Hc * Hc * 2);
  bf16*  Wts_t   = (bf16*)alloc((size_t)2 * Hc * Hc * 2);    // Wtrg^T | Wsrc^T
  bf16*  Wvec_t  = (bf16*)alloc((size_t)2 * Hc * Hc * 2);
  bf16*  Ws_t    = (bf16*)alloc((size_t)2 * Hc * Hc * 2);
  bf16*  Wo_t    = (bf16*)alloc((size_t)3 * Hc * Hc * 2);
  int*   deg     = (int*)alloc(2048 * 4);
  int*   cursor  = (int*)alloc(2048 * 4);
  int*   rowptr  = (int*)alloc(2049 * 4);
  int*   eids    = (int*)alloc(Ec * 4);

  float* out_dx   = (float*)d_out;
  float* out_dvec = (float*)d_out + 524288;
  float* out_df   = (float*)d_out + 4718592;

  // CSR build
  hipMemsetAsync(deg, 0, 2048 * 4, stream);
  hipMemsetAsync(cursor, 0, 2048 * 4, stream);
  hist_k<<<Ec / 256, 256, 0, stream>>>(ei, deg);
  scan_k<<<1, 256, 0, stream>>>(deg, rowptr);
  fill_k<<<Ec / 256, 256, 0, stream>>>(ei, rowptr, cursor, eids);

  // weight prep (transpose + cvt)
  wprep_k<<<dim3(8, 8), 256, 0, stream>>>(Wq, Wqkv_t, Hc, Hc);
  wprep_k<<<dim3(8, 8), 256, 0, stream>>>(Wk, Wqkv_t + 65536, Hc, Hc);
  wprep_k<<<dim3(8, 8), 256, 0, stream>>>(Wv, Wqkv_t + 131072, Hc, Hc);
  wprep_k<<<dim3(8, 8), 256, 0, stream>>>(Wao, Wao_t, Hc, Hc);
  wprep_k<<<dim3(8, 8), 256, 0, stream>>>(Wdv, Wdv_t, Hc, Hc);
  wprep_k<<<dim3(8, 8), 256, 0, stream>>>(Wf, Wf_t, Hc, Hc);
  wprep_k<<<dim3(8, 8), 256, 0, stream>>>(Wtrg, Wts_t, Hc, Hc);
  wprep_k<<<dim3(8, 8), 256, 0, stream>>>(Wsrc, Wts_t + 65536, Hc, Hc);
  wprep_k<<<dim3(8, 16), 256, 0, stream>>>(Wvec, Wvec_t, Hc, 2 * Hc);
  wprep_k<<<dim3(8, 16), 256, 0, stream>>>(Ws, Ws_t, Hc, 2 * Hc);
  wprep_k<<<dim3(8, 24), 256, 0, stream>>>(Wo, Wo_t, Hc, 3 * Hc);

  // input conversions
  cvt_k<<<Ec * Hc / 1024, 256, 0, stream>>>(f_ij, f_bf, Ec * Hc);
  cvt_k<<<BNc * VDc * Hc / 1024, 256, 0, stream>>>(vec, vec_bf, BNc * VDc * Hc);

  // 1. LayerNorm -> bf16
  ln_k<<<BNc, 256, 0, stream>>>(x, ln_w, ln_b, xn_bf);

  // 2. fused q|k|v projection (one MFMA GEMM, N=768)
  mgemm_k<0, bf16><<<dim3(16, 6), 256, 0, stream>>>(xn_bf, Wqkv_t, nullptr, qkv_bf, BNc, Hc, 3 * Hc);

  // 3. MFMA attention
  attn_mfma_k<<<Bc * NHc, 256, 0, stream>>>(qkv_bf, attn_bf);

  // 4. v = attn @ Wao
  mgemm_k<0, float><<<dim3(16, 2), 256, 0, stream>>>(attn_bf, Wao_t, nullptr, vbuf, BNc, Hc, Hc);

  // 5. dv = silu(f_ij @ Wdv + bdv)
  mgemm_k<1, bf16><<<dim3(128, 2), 256, 0, stream>>>(f_bf, Wdv_t, bdv, dv_bf, Ec, Hc, Hc);

  // 6. vp = vec @ Wvec ; vec_sum
  mgemm_k<0, bf16><<<dim3(128, 4), 256, 0, stream>>>(vec_bf, Wvec_t, nullptr, vp_bf, BNc * VDc, Hc, 2 * Hc);
  vecsum_k<<<2048, 256, 0, stream>>>(vp_bf, vsum);

  // 7. v_j
  vj_k<<<Ec, 256, 0, stream>>>(vbuf, dv_bf, ei, r_ij, vj_bf);

  // 8. x_agg via CSR gather
  xagg_k<<<BNc, 256, 0, stream>>>(vj_bf, rowptr, eids, xagg_bf);

  // 9. s12 = silu(v_j @ Ws + bs)
  mgemm_k<1, bf16><<<dim3(128, 4), 256, 0, stream>>>(vj_bf, Ws_t, bs, s12_bf, Ec, Hc, 2 * Hc);

  // 10. o = x_agg @ Wo + bo
  mgemm_k<0, float><<<dim3(16, 6), 256, 0, stream>>>(xagg_bf, Wo_t, bo, obuf, BNc, Hc, 3 * Hc);

  // 11. dx
  dx_k<<<2048, 256, 0, stream>>>(vsum, obuf, out_dx);

  // 12. fused vec_agg + dvec epilogue
  dvec_agg_k<<<BNc, 256, 0, stream>>>(vec_bf, s12_bf, d_ij, ei, rowptr, eids,
                                      vp_bf, obuf, out_dvec);

  // 13. df path (Ttrg|Tsrc in one GEMM, N=512)
  mgemm_k<1, bf16><<<dim3(128, 2), 256, 0, stream>>>(f_bf, Wf_t, bf_, fW_bf, Ec, Hc, Hc);
  mgemm_k<0, bf16><<<dim3(128, 4), 256, 0, stream>>>(vec_bf, Wts_t, nullptr, T_bf, BNc * VDc, Hc, 2 * Hc);
  df_k<<<Ec, 256, 0, stream>>>(T_bf, d_ij, fW_bf, ei, out_df);

  (void)in_sizes; (void)n_in; (void)out_size; (void)ws_size;
}

// Round 6
// 326.809 us; speedup vs baseline: 2.3116x; 1.0852x over previous
//
#include <hip/hip_runtime.h>
#include <hip/hip_bf16.h>
#include <math.h>

typedef __hip_bfloat16 bf16;
#define DEV __device__ __forceinline__
DEV float silu_f(float x) { return x / (1.0f + __expf(-x)); }
DEV float toF(bf16 x) { return __bfloat162float(x); }
DEV void storeF(float* p, float v) { *p = v; }
DEV void storeF(bf16* p, float v) { *p = __float2bfloat16(v); }

constexpr int Bc = 8, Nc = 256, BNc = 2048, Ec = 16384;
constexpr int Hc = 256, NHc = 8, HDc = 32, VDc = 8;

typedef __attribute__((ext_vector_type(8))) short short8;
typedef __attribute__((ext_vector_type(4))) float floatx4;

DEV void async_copy16(const void* g, void* l) {
  __builtin_amdgcn_global_load_lds(
      (const __attribute__((address_space(1))) void*)g,
      (__attribute__((address_space(3))) void*)l, 16, 0, 0);
}

// ---------------- single-block CSR build (zero+hist+scan+fill) ----------------
__global__ __launch_bounds__(1024) void csr_k(const int* __restrict__ ei,
                                              int* __restrict__ rowptr,
                                              int* __restrict__ eids) {
  __shared__ int deg[2048];
  __shared__ int cur[2048];
  __shared__ int ps[1024];
  __shared__ int rp[2048];
  int t = threadIdx.x;
  for (int i = t; i < 2048; i += 1024) { deg[i] = 0; cur[i] = 0; }
  __syncthreads();
  for (int e = t; e < Ec; e += 1024) atomicAdd(&deg[ei[Ec + e]], 1);
  __syncthreads();
  int s0 = deg[2 * t], s1 = deg[2 * t + 1];
  ps[t] = s0 + s1;
  __syncthreads();
  for (int off = 1; off < 1024; off <<= 1) {
    int v = (t >= off) ? ps[t - off] : 0;
    __syncthreads();
    ps[t] += v;
    __syncthreads();
  }
  int base = (t == 0) ? 0 : ps[t - 1];
  rp[2 * t] = base; rp[2 * t + 1] = base + s0;
  rowptr[2 * t] = base; rowptr[2 * t + 1] = base + s0;
  if (t == 1023) rowptr[2048] = Ec;
  __syncthreads();
  for (int e = t; e < Ec; e += 1024) {
    int d = ei[Ec + e];
    int p = atomicAdd(&cur[d], 1);
    eids[rp[d] + p] = e;
  }
}

// ---------------- batched weight prep: out[n*K+k] = bf16(in[k*N+n]) ----------------
struct WDesc { const float* in; bf16* out; int K, N; };
struct WAll { WDesc d[11]; };

__global__ __launch_bounds__(256) void wprep_all_k(WAll wa) {
  WDesc wd = wa.d[blockIdx.z];
  if ((int)blockIdx.y * 32 >= wd.N) return;
  __shared__ float t[32][33];
  int k0 = blockIdx.x * 32, n0 = blockIdx.y * 32;
  int tx = threadIdx.x & 31, ty = threadIdx.x >> 5;
#pragma unroll
  for (int i = 0; i < 32; i += 8)
    t[ty + i][tx] = wd.in[(size_t)(k0 + ty + i) * wd.N + n0 + tx];
  __syncthreads();
#pragma unroll
  for (int i = 0; i < 32; i += 8)
    wd.out[(size_t)(n0 + ty + i) * wd.K + k0 + tx] = __float2bfloat16(t[tx][ty + i]);
}

// ---------------- dual fp32 -> bf16 convert (two 4.19M-elem arrays) ----------------
__global__ __launch_bounds__(256) void cvt2_k(const float* __restrict__ a,
                                              bf16* __restrict__ ao,
                                              const float* __restrict__ b,
                                              bf16* __restrict__ bo) {
  int blk = blockIdx.x;
  const float* in = (blk < 4096) ? a : b;
  bf16* out = (blk < 4096) ? ao : bo;
  int i = ((blk & 4095) * 256 + threadIdx.x) * 4;
  float4 v = *(const float4*)&in[i];
  union { bf16 x[4]; uint2 u; } o;
  o.x[0] = __float2bfloat16(v.x); o.x[1] = __float2bfloat16(v.y);
  o.x[2] = __float2bfloat16(v.z); o.x[3] = __float2bfloat16(v.w);
  *(uint2*)&out[i] = o.u;
}

// ---------------- LayerNorm -> bf16 ----------------
__global__ __launch_bounds__(256) void ln_k(const float* __restrict__ x,
    const float* __restrict__ w, const float* __restrict__ b,
    bf16* __restrict__ xn) {
  int row = blockIdx.x, h = threadIdx.x;
  float v = x[(size_t)row * Hc + h];
  __shared__ float sm[256];
  sm[h] = v; __syncthreads();
  for (int s = 128; s > 0; s >>= 1) { if (h < s) sm[h] += sm[h + s]; __syncthreads(); }
  float mu = sm[0] * (1.0f / 256.0f);
  __syncthreads();
  float d = v - mu;
  sm[h] = d * d; __syncthreads();
  for (int s = 128; s > 0; s >>= 1) { if (h < s) sm[h] += sm[h + s]; __syncthreads(); }
  float var = sm[0] * (1.0f / 256.0f);
  float r = rsqrtf(var + 1e-5f);
  xn[(size_t)row * Hc + h] = __float2bfloat16(d * r * w[h] + b[h]);
}

// ---------------- generic MFMA GEMM: C = act(A @ Bt^T + bias) ----------------
template <int ACT, typename TC>
__global__ __launch_bounds__(256) void mgemm_k(
    const bf16* __restrict__ A, const bf16* __restrict__ Bt,
    const float* __restrict__ bias, TC* __restrict__ C,
    int M, int K, int N) {
  __shared__ bf16 Als[128 * 32];
  __shared__ bf16 Bls[128 * 32];
  int tid = threadIdx.x;
  int lane = tid & 63, w = tid >> 6;
  int m0 = blockIdx.x * 128, n0 = blockIdx.y * 128;
  int wm = (w & 1) * 64, wn = (w >> 1) * 64;
  int fm = lane & 15, g = lane >> 4;
  floatx4 acc[4][4] = {};
  for (int k0 = 0; k0 < K; k0 += 32) {
#pragma unroll
    for (int t = 0; t < 2; ++t) {
      int c = t * 256 + w * 64 + lane;
      int r = c >> 2, q = c & 3;
      bf16* ldsA = &Als[(t * 256 + w * 64) * 8 + lane * 8];
      bf16* ldsB = &Bls[(t * 256 + w * 64) * 8 + lane * 8];
      async_copy16(A + (size_t)(m0 + r) * K + k0 + q * 8, ldsA);
      async_copy16(Bt + (size_t)(n0 + r) * K + k0 + q * 8, ldsB);
    }
    __syncthreads();
    short8 af[4], bg[4];
#pragma unroll
    for (int i = 0; i < 4; ++i) {
      af[i] = *(const short8*)&Als[(wm + i * 16 + fm) * 32 + g * 8];
      bg[i] = *(const short8*)&Bls[(wn + i * 16 + fm) * 32 + g * 8];
    }
#pragma unroll
    for (int mi = 0; mi < 4; ++mi)
#pragma unroll
      for (int ni = 0; ni < 4; ++ni)
        acc[mi][ni] = __builtin_amdgcn_mfma_f32_16x16x32_bf16(
            af[mi], bg[ni], acc[mi][ni], 0, 0, 0);
    __syncthreads();
  }
#pragma unroll
  for (int mi = 0; mi < 4; ++mi) {
    int row0 = m0 + wm + mi * 16 + g * 4;
#pragma unroll
    for (int ni = 0; ni < 4; ++ni) {
      int col = n0 + wn + ni * 16 + fm;
      float bv = bias ? bias[col] : 0.0f;
#pragma unroll
      for (int r = 0; r < 4; ++r) {
        float v = acc[mi][ni][r] + bv;
        if (ACT) v = silu_f(v);
        storeF(&C[(size_t)(row0 + r) * N + col], v);
      }
    }
  }
}

// ---------------- dv|fW GEMM with fused vj epilogue ----------------
// A = f_bf [16384][256]; Bt = Wdv^T|Wf^T [512][256].
// cols 0..255: vj[e][col] = vbuf[src[e]][col] * cut(e) * silu(acc+bdv)
// cols 256..511: fW[e][col-256] = silu(acc+bf)
__global__ __launch_bounds__(256) void gemm_dvfw_k(
    const bf16* __restrict__ A, const bf16* __restrict__ Bt,
    const float* __restrict__ bdv, const float* __restrict__ bf_,
    const int* __restrict__ ei, const float* __restrict__ r_ij,
    const float* __restrict__ vbuf,
    bf16* __restrict__ vj, bf16* __restrict__ fW) {
  constexpr int K = 256, N = 512;
  __shared__ bf16 Als[128 * 32];
  __shared__ bf16 Bls[128 * 32];
  int tid = threadIdx.x;
  int lane = tid & 63, w = tid >> 6;
  int m0 = blockIdx.x * 128, n0 = blockIdx.y * 128;
  int wm = (w & 1) * 64, wn = (w >> 1) * 64;
  int fm = lane & 15, g = lane >> 4;
  floatx4 acc[4][4] = {};
  for (int k0 = 0; k0 < K; k0 += 32) {
#pragma unroll
    for (int t = 0; t < 2; ++t) {
      int c = t * 256 + w * 64 + lane;
      int r = c >> 2, q = c & 3;
      bf16* ldsA = &Als[(t * 256 + w * 64) * 8 + lane * 8];
      bf16* ldsB = &Bls[(t * 256 + w * 64) * 8 + lane * 8];
      async_copy16(A + (size_t)(m0 + r) * K + k0 + q * 8, ldsA);
      async_copy16(Bt + (size_t)(n0 + r) * K + k0 + q * 8, ldsB);
    }
    __syncthreads();
    short8 af[4], bg[4];
#pragma unroll
    for (int i = 0; i < 4; ++i) {
      af[i] = *(const short8*)&Als[(wm + i * 16 + fm) * 32 + g * 8];
      bg[i] = *(const short8*)&Bls[(wn + i * 16 + fm) * 32 + g * 8];
    }
#pragma unroll
    for (int mi = 0; mi < 4; ++mi)
#pragma unroll
      for (int ni = 0; ni < 4; ++ni)
        acc[mi][ni] = __builtin_amdgcn_mfma_f32_16x16x32_bf16(
            af[mi], bg[ni], acc[mi][ni], 0, 0, 0);
    __syncthreads();
  }
  bool isVj = (n0 < 256);  // block-uniform
#pragma unroll
  for (int mi = 0; mi < 4; ++mi) {
    int row0 = m0 + wm + mi * 16 + g * 4;
#pragma unroll
    for (int r = 0; r < 4; ++r) {
      int e = row0 + r;
      int src = 0; float cut = 0.f;
      if (isVj) {
        src = ei[e];
        float rr = r_ij[e];
        cut = (rr < 5.0f) ? 0.5f * (cosf(0.6283185307179586f * rr) + 1.0f) : 0.0f;
      }
#pragma unroll
      for (int ni = 0; ni < 4; ++ni) {
        int col = n0 + wn + ni * 16 + fm;
        if (isVj) {
          float v = silu_f(acc[mi][ni][r] + bdv[col]);
          vj[(size_t)e * 256 + col] =
              __float2bfloat16(vbuf[(size_t)src * 256 + col] * cut * v);
        } else {
          float v = silu_f(acc[mi][ni][r] + bf_[col - 256]);
          fW[(size_t)e * 256 + (col - 256)] = __float2bfloat16(v);
        }
      }
    }
  }
}

// ---------------- MFMA attention per (b,h) ----------------
__global__ __launch_bounds__(256) void attn_mfma_k(
    const bf16* __restrict__ qkv, bf16* __restrict__ ob) {
  constexpr int QS = 768;
  int b = blockIdx.x >> 3, h = blockIdx.x & 7;
  int tid = threadIdx.x, lane = tid & 63, w = tid >> 6;
  int fm = lane & 15, g = lane >> 4;
  __shared__ bf16 Vt[32][264];
  __shared__ bf16 Ps[4][64][72];
  const bf16* qb = qkv + (size_t)b * 256 * QS + h * 32;
  const bf16* kb = qb + 256;
  const bf16* vb = qb + 512;
#pragma unroll
  for (int c = 0; c < 4; ++c) {
    int chunk = c * 256 + tid;
    int j = chunk >> 2, part = chunk & 3;
    union { short8 v; bf16 x[8]; } t;
    t.v = *(const short8*)(vb + (size_t)j * QS + part * 8);
#pragma unroll
    for (int i = 0; i < 8; ++i) Vt[part * 8 + i][j] = t.x[i];
  }
  __syncthreads();
  short8 af[4];
#pragma unroll
  for (int mi = 0; mi < 4; ++mi)
    af[mi] = *(const short8*)(qb + (size_t)(w * 64 + mi * 16 + fm) * QS + g * 8);
  floatx4 oacc[4][2] = {};
  for (int jt = 0; jt < 4; ++jt) {
#pragma unroll
    for (int ni = 0; ni < 4; ++ni) {
      short8 bg = *(const short8*)(kb + (size_t)(jt * 64 + ni * 16 + fm) * QS + g * 8);
#pragma unroll
      for (int mi = 0; mi < 4; ++mi) {
        floatx4 z = {0.f, 0.f, 0.f, 0.f};
        floatx4 s = __builtin_amdgcn_mfma_f32_16x16x32_bf16(af[mi], bg, z, 0, 0, 0);
#pragma unroll
        for (int r = 0; r < 4; ++r) {
          float v = silu_f(s[r] * 0.17677669529663687f);
          Ps[w][mi * 16 + g * 4 + r][ni * 16 + fm] = __float2bfloat16(v);
        }
      }
    }
#pragma unroll
    for (int kt = 0; kt < 2; ++kt) {
      short8 bv0 = *(const short8*)&Vt[fm][jt * 64 + kt * 32 + g * 8];
      short8 bv1 = *(const short8*)&Vt[16 + fm][jt * 64 + kt * 32 + g * 8];
#pragma unroll
      for (int mi = 0; mi < 4; ++mi) {
        short8 ap = *(const short8*)&Ps[w][mi * 16 + fm][kt * 32 + g * 8];
        oacc[mi][0] = __builtin_amdgcn_mfma_f32_16x16x32_bf16(ap, bv0, oacc[mi][0], 0, 0, 0);
        oacc[mi][1] = __builtin_amdgcn_mfma_f32_16x16x32_bf16(ap, bv1, oacc[mi][1], 0, 0, 0);
      }
    }
  }
#pragma unroll
  for (int mi = 0; mi < 4; ++mi)
#pragma unroll
    for (int ni = 0; ni < 2; ++ni)
#pragma unroll
      for (int r = 0; r < 4; ++r) {
        int row = w * 64 + mi * 16 + g * 4 + r;
        int d = ni * 16 + fm;
        ob[((size_t)(b * 256 + row)) * 256 + h * 32 + d] =
            __float2bfloat16(oacc[mi][ni][r] * (1.0f / 256.0f));
      }
}

// ---------------- x_agg via CSR gather -> bf16 ----------------
__global__ __launch_bounds__(256) void xagg_k(const bf16* __restrict__ vj,
                                              const int* __restrict__ rowptr,
                                              const int* __restrict__ eids,
                                              bf16* __restrict__ xagg_bf) {
  int n = blockIdx.x, h = threadIdx.x;
  float acc = 0.f;
  int lo = rowptr[n], hi = rowptr[n + 1];
  for (int i = lo; i < hi; ++i) {
    int e = eids[i];
    acc += toF(vj[(size_t)e * Hc + h]);
  }
  xagg_bf[(size_t)n * Hc + h] = __float2bfloat16(acc);
}

// ---------------- fused vec_agg gather + dvec epilogue ----------------
// vpT: [16384][1024] = vec1|vec3|Ttrg|Tsrc
__global__ __launch_bounds__(256) void dvec_agg_k(
    const bf16* __restrict__ vec_bf, const bf16* __restrict__ s12,
    const float* __restrict__ d_ij, const int* __restrict__ ei,
    const int* __restrict__ rowptr, const int* __restrict__ eids,
    const bf16* __restrict__ vpT, const float* __restrict__ o,
    float* __restrict__ out) {
  int n = blockIdx.x, h = threadIdx.x;
  float acc[8] = {};
  int lo = rowptr[n], hi = rowptr[n + 1];
  for (int i = lo; i < hi; ++i) {
    int e = eids[i];
    int src = ei[e];
    float s1 = toF(s12[(size_t)e * 512 + h]);
    float s2 = toF(s12[(size_t)e * 512 + 256 + h]);
#pragma unroll
    for (int vd = 0; vd < 8; ++vd) {
      float dd = d_ij[(size_t)e * VDc + vd];
      acc[vd] += toF(vec_bf[((size_t)src * VDc + vd) * Hc + h]) * s1 + s2 * dd;
    }
  }
  float o1 = o[(size_t)n * 768 + h];
#pragma unroll
  for (int vd = 0; vd < 8; ++vd) {
    float v3 = toF(vpT[((size_t)n * VDc + vd) * 1024 + 256 + h]);
    out[((size_t)n * VDc + vd) * Hc + h] = v3 * o1 + acc[vd];
  }
}

// ---------------- dx = (sum_vd vec1) * o2 + o3 (fused vecsum) ----------------
__global__ __launch_bounds__(256) void dxsum_k(const bf16* __restrict__ vpT,
                                               const float* __restrict__ o,
                                               float* __restrict__ out) {
  int idx = blockIdx.x * 256 + threadIdx.x;
  int row = idx >> 8, col = idx & 255;
  float s = 0.f;
#pragma unroll
  for (int vd = 0; vd < 8; ++vd)
    s += toF(vpT[((size_t)row * 8 + vd) * 1024 + col]);
  float o2 = o[(size_t)row * 768 + 256 + col];
  float o3 = o[(size_t)row * 768 + 512 + col];
  out[idx] = s * o2 + o3;
}

// ---------------- df = fW * (sum t1*t2 - p1*p2) ----------------
__global__ __launch_bounds__(256) void df_k(
    const bf16* __restrict__ vpT, const float* __restrict__ d_ij,
    const bf16* __restrict__ fW, const int* __restrict__ ei,
    float* __restrict__ out) {
  int e = blockIdx.x, h = threadIdx.x;
  int src = ei[e], dst = ei[Ec + e];
  float S = 0.f, p1 = 0.f, p2 = 0.f;
#pragma unroll
  for (int vd = 0; vd < 8; ++vd) {
    float t1 = toF(vpT[((size_t)dst * 8 + vd) * 1024 + 512 + h]);
    float t2 = toF(vpT[((size_t)src * 8 + vd) * 1024 + 768 + h]);
    float dd = d_ij[(size_t)e * 8 + vd];
    S += t1 * t2; p1 += t1 * dd; p2 += t2 * dd;
  }
  out[(size_t)e * Hc + h] = toF(fW[(size_t)e * Hc + h]) * (S - p1 * p2);
}

extern "C" void kernel_launch(void* const* d_in, const int* in_sizes, int n_in,
                              void* d_out, int out_size, void* d_ws, size_t ws_size,
                              hipStream_t stream) {
  const float* x    = (const float*)d_in[0];
  const float* vec  = (const float*)d_in[1];
  const int*   ei   = (const int*)d_in[2];
  const float* r_ij = (const float*)d_in[3];
  const float* f_ij = (const float*)d_in[4];
  const float* d_ij = (const float*)d_in[5];
  const float* ln_w = (const float*)d_in[7];
  const float* ln_b = (const float*)d_in[8];
  const float* Wq   = (const float*)d_in[9];
  const float* Wk   = (const float*)d_in[10];
  const float* Wv   = (const float*)d_in[11];
  const float* Wao  = (const float*)d_in[12];
  const float* Wvec = (const float*)d_in[13];
  const float* Wdv  = (const float*)d_in[14];
  const float* bdv  = (const float*)d_in[15];
  const float* Ws   = (const float*)d_in[16];
  const float* bs   = (const float*)d_in[17];
  const float* Wo   = (const float*)d_in[18];
  const float* bo   = (const float*)d_in[19];
  const float* Wf   = (const float*)d_in[20];
  const float* bf_  = (const float*)d_in[21];
  const float* Wsrc = (const float*)d_in[22];
  const float* Wtrg = (const float*)d_in[23];

  char* p = (char*)d_ws;
  auto alloc = [&](size_t bytes) {
    char* r = p; p += (bytes + 255) & ~(size_t)255; return r;
  };
  bf16*  xn_bf   = (bf16*)alloc((size_t)BNc * Hc * 2);
  bf16*  qkv_bf  = (bf16*)alloc((size_t)BNc * 3 * Hc * 2);     // [2048][768]
  bf16*  attn_bf = (bf16*)alloc((size_t)BNc * Hc * 2);
  float* vbuf    = (float*)alloc((size_t)BNc * Hc * 4);
  bf16*  xagg_bf = (bf16*)alloc((size_t)BNc * Hc * 2);
  float* obuf    = (float*)alloc((size_t)BNc * 3 * Hc * 4);
  bf16*  f_bf    = (bf16*)alloc((size_t)Ec * Hc * 2);
  bf16*  vec_bf  = (bf16*)alloc((size_t)BNc * VDc * Hc * 2);
  bf16*  vpT     = (bf16*)alloc((size_t)Ec * 1024 * 2);        // [16384][1024] v1|v3|Tt|Ts
  bf16*  vj_bf   = (bf16*)alloc((size_t)Ec * Hc * 2);
  bf16*  s12_bf  = (bf16*)alloc((size_t)Ec * 2 * Hc * 2);
  bf16*  fW_bf   = (bf16*)alloc((size_t)Ec * Hc * 2);
  bf16*  Wqkv_t  = (bf16*)alloc((size_t)3 * Hc * Hc * 2);
  bf16*  Wao_t   = (bf16*)alloc((size_t)Hc * Hc * 2);
  bf16*  Wdvf_t  = (bf16*)alloc((size_t)2 * Hc * Hc * 2);      // Wdv^T|Wf^T
  bf16*  Wvt_t   = (bf16*)alloc((size_t)4 * Hc * Hc * 2);      // Wvec^T|Wtrg^T|Wsrc^T
  bf16*  Ws_t    = (bf16*)alloc((size_t)2 * Hc * Hc * 2);
  bf16*  Wo_t    = (bf16*)alloc((size_t)3 * Hc * Hc * 2);
  int*   rowptr  = (int*)alloc(2049 * 4);
  int*   eids    = (int*)alloc(Ec * 4);

  float* out_dx   = (float*)d_out;
  float* out_dvec = (float*)d_out + 524288;
  float* out_df   = (float*)d_out + 4718592;

  // 1. CSR build (single block)
  csr_k<<<1, 1024, 0, stream>>>(ei, rowptr, eids);

  // 2. batched weight prep
  WAll wa;
  wa.d[0]  = {Wq,   Wqkv_t,           Hc, Hc};
  wa.d[1]  = {Wk,   Wqkv_t + 65536,   Hc, Hc};
  wa.d[2]  = {Wv,   Wqkv_t + 131072,  Hc, Hc};
  wa.d[3]  = {Wao,  Wao_t,            Hc, Hc};
  wa.d[4]  = {Wdv,  Wdvf_t,           Hc, Hc};
  wa.d[5]  = {Wf,   Wdvf_t + 65536,   Hc, Hc};
  wa.d[6]  = {Wvec, Wvt_t,            Hc, 2 * Hc};
  wa.d[7]  = {Wtrg, Wvt_t + 131072,   Hc, Hc};
  wa.d[8]  = {Wsrc, Wvt_t + 196608,   Hc, Hc};
  wa.d[9]  = {Ws,   Ws_t,             Hc, 2 * Hc};
  wa.d[10] = {Wo,   Wo_t,             Hc, 3 * Hc};
  wprep_all_k<<<dim3(8, 24, 11), 256, 0, stream>>>(wa);

  // 3. input conversions (f_ij and vec, both 4.19M elems)
  cvt2_k<<<8192, 256, 0, stream>>>(f_ij, f_bf, vec, vec_bf);

  // 4. LayerNorm -> bf16
  ln_k<<<BNc, 256, 0, stream>>>(x, ln_w, ln_b, xn_bf);

  // 5. fused q|k|v projection
  mgemm_k<0, bf16><<<dim3(16, 6), 256, 0, stream>>>(xn_bf, Wqkv_t, nullptr, qkv_bf, BNc, Hc, 3 * Hc);

  // 6. MFMA attention
  attn_mfma_k<<<Bc * NHc, 256, 0, stream>>>(qkv_bf, attn_bf);

  // 7. v = attn @ Wao (fp32 out, gathered by dvfw epilogue)
  mgemm_k<0, float><<<dim3(16, 2), 256, 0, stream>>>(attn_bf, Wao_t, nullptr, vbuf, BNc, Hc, Hc);

  // 8. vpT = vec @ (Wvec|Wtrg|Wsrc)  [16384][1024]
  mgemm_k<0, bf16><<<dim3(128, 8), 256, 0, stream>>>(vec_bf, Wvt_t, nullptr, vpT, Ec, Hc, 4 * Hc);

  // 9. dv|fW GEMM with fused vj epilogue
  gemm_dvfw_k<<<dim3(128, 4), 256, 0, stream>>>(f_bf, Wdvf_t, bdv, bf_, ei, r_ij,
                                                vbuf, vj_bf, fW_bf);

  // 10. x_agg via CSR gather
  xagg_k<<<BNc, 256, 0, stream>>>(vj_bf, rowptr, eids, xagg_bf);

  // 11. s12 = silu(v_j @ Ws + bs)
  mgemm_k<1, bf16><<<dim3(128, 4), 256, 0, stream>>>(vj_bf, Ws_t, bs, s12_bf, Ec, Hc, 2 * Hc);

  // 12. o = x_agg @ Wo + bo
  mgemm_k<0, float><<<dim3(16, 6), 256, 0, stream>>>(xagg_bf, Wo_t, bo, obuf, BNc, Hc, 3 * Hc);

  // 13. dx (fused vecsum)
  dxsum_k<<<2048, 256, 0, stream>>>(vpT, obuf, out_dx);

  // 14. fused vec_agg + dvec epilogue
  dvec_agg_k<<<BNc, 256, 0, stream>>>(vec_bf, s12_bf, d_ij, ei, rowptr, eids,
                                      vpT, obuf, out_dvec);

  // 15. df
  df_k<<<Ec, 256, 0, stream>>>(vpT, d_ij, fW_bf, ei, out_df);

  (void)in_sizes; (void)n_in; (void)out_size; (void)ws_size;
}

// Round 7
// 302.612 us; speedup vs baseline: 2.4964x; 1.0800x over previous
//
#include <hip/hip_runtime.h>
#include <hip/hip_bf16.h>
#include <math.h>

typedef __hip_bfloat16 bf16;
#define DEV __device__ __forceinline__
DEV float silu_f(float x) { return x / (1.0f + __expf(-x)); }
DEV float toF(bf16 x) { return __bfloat162float(x); }
DEV void storeF(float* p, float v) { *p = v; }
DEV void storeF(bf16* p, float v) { *p = __float2bfloat16(v); }

constexpr int Bc = 8, Nc = 256, BNc = 2048, Ec = 16384;
constexpr int Hc = 256, NHc = 8, HDc = 32, VDc = 8;

typedef __attribute__((ext_vector_type(8))) short short8;
typedef __attribute__((ext_vector_type(4))) float floatx4;
union sh8 { short8 v; bf16 x[8]; };

DEV void async_copy16(const void* g, void* l) {
  __builtin_amdgcn_global_load_lds(
      (const __attribute__((address_space(1))) void*)g,
      (__attribute__((address_space(3))) void*)l, 16, 0, 0);
}

// ================= device bodies =================

// ---- CSR build (single block, 256 threads, all in LDS) ----
DEV void csr_body(const int* __restrict__ ei, int* __restrict__ rowptr,
                  int* __restrict__ eids, int* sm) {
  int* deg = sm;         // 2048
  int* cur = sm + 2048;  // 2048
  int* rp  = sm + 4096;  // 2048
  int* ps  = sm + 6144;  // 256
  int t = threadIdx.x;
  for (int i = t; i < 2048; i += 256) { deg[i] = 0; cur[i] = 0; }
  __syncthreads();
  for (int e = t; e < Ec; e += 256) atomicAdd(&deg[ei[Ec + e]], 1);
  __syncthreads();
  int loc[8], s = 0;
#pragma unroll
  for (int i = 0; i < 8; ++i) { loc[i] = s; s += deg[t * 8 + i]; }
  ps[t] = s;
  __syncthreads();
  for (int off = 1; off < 256; off <<= 1) {
    int v = (t >= off) ? ps[t - off] : 0;
    __syncthreads();
    ps[t] += v;
    __syncthreads();
  }
  int base = (t == 0) ? 0 : ps[t - 1];
#pragma unroll
  for (int i = 0; i < 8; ++i) {
    rp[t * 8 + i] = base + loc[i];
    rowptr[t * 8 + i] = base + loc[i];
  }
  if (t == 255) rowptr[2048] = Ec;
  __syncthreads();
  for (int e = t; e < Ec; e += 256) {
    int d = ei[Ec + e];
    int p = atomicAdd(&cur[d], 1);
    eids[rp[d] + p] = e;
  }
}

// ---- weight transpose+cvt ----
struct WDesc { const float* in; bf16* out; int K, N; };

DEV void wprep_body(WDesc wd, int by, int bx, float* sm) {
  if (by * 32 >= wd.N) return;
  float (*t)[33] = (float (*)[33])sm;
  int k0 = bx * 32, n0 = by * 32;
  int tx = threadIdx.x & 31, ty = threadIdx.x >> 5;
#pragma unroll
  for (int i = 0; i < 32; i += 8)
    t[ty + i][tx] = wd.in[(size_t)(k0 + ty + i) * wd.N + n0 + tx];
  __syncthreads();
#pragma unroll
  for (int i = 0; i < 32; i += 8)
    wd.out[(size_t)(n0 + ty + i) * wd.K + k0 + tx] = __float2bfloat16(t[tx][ty + i]);
}

// ---- fp32 -> bf16 ----
DEV void cvt_body(const float* __restrict__ in, bf16* __restrict__ out, int blk) {
  int i = (blk * 256 + threadIdx.x) * 4;
  float4 v = *(const float4*)&in[i];
  union { bf16 x[4]; uint2 u; } o;
  o.x[0] = __float2bfloat16(v.x); o.x[1] = __float2bfloat16(v.y);
  o.x[2] = __float2bfloat16(v.z); o.x[3] = __float2bfloat16(v.w);
  *(uint2*)&out[i] = o.u;
}

// ---- LayerNorm ----
DEV void ln_body(const float* __restrict__ x, const float* __restrict__ w,
                 const float* __restrict__ b, bf16* __restrict__ xn,
                 int row, float* sm) {
  int h = threadIdx.x;
  float v = x[(size_t)row * Hc + h];
  sm[h] = v; __syncthreads();
  for (int s = 128; s > 0; s >>= 1) { if (h < s) sm[h] += sm[h + s]; __syncthreads(); }
  float mu = sm[0] * (1.0f / 256.0f);
  __syncthreads();
  float d = v - mu;
  sm[h] = d * d; __syncthreads();
  for (int s = 128; s > 0; s >>= 1) { if (h < s) sm[h] += sm[h + s]; __syncthreads(); }
  float var = sm[0] * (1.0f / 256.0f);
  float r = rsqrtf(var + 1e-5f);
  xn[(size_t)row * Hc + h] = __float2bfloat16(d * r * w[h] + b[h]);
}

// ---- MFMA GEMM tile body: C[m0:m0+128, n0:n0+128] = act(A@Bt^T + bias) ----
template <int ACT, typename TC>
DEV void mgemm_body(const bf16* __restrict__ A, const bf16* __restrict__ Bt,
                    const float* __restrict__ bias, TC* __restrict__ C,
                    int M, int K, int N, int m0, int n0,
                    bf16* Als, bf16* Bls) {
  int tid = threadIdx.x;
  int lane = tid & 63, w = tid >> 6;
  int wm = (w & 1) * 64, wn = (w >> 1) * 64;
  int fm = lane & 15, g = lane >> 4;
  floatx4 acc[4][4] = {};
  for (int k0 = 0; k0 < K; k0 += 32) {
#pragma unroll
    for (int t = 0; t < 2; ++t) {
      int c = t * 256 + w * 64 + lane;
      int r = c >> 2, q = c & 3;
      bf16* ldsA = &Als[(t * 256 + w * 64) * 8 + lane * 8];
      bf16* ldsB = &Bls[(t * 256 + w * 64) * 8 + lane * 8];
      async_copy16(A + (size_t)(m0 + r) * K + k0 + q * 8, ldsA);
      async_copy16(Bt + (size_t)(n0 + r) * K + k0 + q * 8, ldsB);
    }
    __syncthreads();
    short8 af[4], bg[4];
#pragma unroll
    for (int i = 0; i < 4; ++i) {
      af[i] = *(const short8*)&Als[(wm + i * 16 + fm) * 32 + g * 8];
      bg[i] = *(const short8*)&Bls[(wn + i * 16 + fm) * 32 + g * 8];
    }
#pragma unroll
    for (int mi = 0; mi < 4; ++mi)
#pragma unroll
      for (int ni = 0; ni < 4; ++ni)
        acc[mi][ni] = __builtin_amdgcn_mfma_f32_16x16x32_bf16(
            af[mi], bg[ni], acc[mi][ni], 0, 0, 0);
    __syncthreads();
  }
#pragma unroll
  for (int mi = 0; mi < 4; ++mi) {
    int row0 = m0 + wm + mi * 16 + g * 4;
#pragma unroll
    for (int ni = 0; ni < 4; ++ni) {
      int col = n0 + wn + ni * 16 + fm;
      float bv = bias ? bias[col] : 0.0f;
#pragma unroll
      for (int r = 0; r < 4; ++r) {
        float v = acc[mi][ni][r] + bv;
        if (ACT) v = silu_f(v);
        storeF(&C[(size_t)(row0 + r) * N + col], v);
      }
    }
  }
}

// ---- vectorized gather bodies (8 cols / thread, short8 loads) ----
DEV void xagg_body(const bf16* __restrict__ vj, const int* __restrict__ rowptr,
                   const int* __restrict__ eids, bf16* __restrict__ xagg, int blk) {
  int node = blk * 8 + (threadIdx.x >> 5);
  int tx = threadIdx.x & 31;
  float acc[8] = {};
  int lo = rowptr[node], hi = rowptr[node + 1];
  for (int i = lo; i < hi; ++i) {
    sh8 vv; vv.v = *(const short8*)&vj[(size_t)eids[i] * 256 + tx * 8];
#pragma unroll
    for (int c = 0; c < 8; ++c) acc[c] += toF(vv.x[c]);
  }
  sh8 o;
#pragma unroll
  for (int c = 0; c < 8; ++c) o.x[c] = __float2bfloat16(acc[c]);
  *(short8*)&xagg[(size_t)node * 256 + tx * 8] = o.v;
}

DEV void df_body(const bf16* __restrict__ vpT, const float* __restrict__ d_ij,
                 const bf16* __restrict__ fW, const int* __restrict__ ei,
                 float* __restrict__ out, int blk) {
  int te = threadIdx.x >> 5, tx = threadIdx.x & 31;
  int e = blk * 8 + te;
  int src = ei[e], dst = ei[Ec + e];
  float S[8] = {}, p1[8] = {}, p2[8] = {};
#pragma unroll
  for (int vd = 0; vd < 8; ++vd) {
    sh8 t1, t2;
    t1.v = *(const short8*)&vpT[((size_t)(dst * 8 + vd)) * 1024 + 512 + tx * 8];
    t2.v = *(const short8*)&vpT[((size_t)(src * 8 + vd)) * 1024 + 768 + tx * 8];
    float dd = d_ij[e * 8 + vd];
#pragma unroll
    for (int c = 0; c < 8; ++c) {
      float a = toF(t1.x[c]), b = toF(t2.x[c]);
      S[c] += a * b; p1[c] += a * dd; p2[c] += b * dd;
    }
  }
  sh8 fw; fw.v = *(const short8*)&fW[(size_t)e * 256 + tx * 8];
  float o[8];
#pragma unroll
  for (int c = 0; c < 8; ++c) o[c] = toF(fw.x[c]) * (S[c] - p1[c] * p2[c]);
  float* dst_p = &out[(size_t)e * 256 + tx * 8];
  *(float4*)dst_p = make_float4(o[0], o[1], o[2], o[3]);
  *(float4*)(dst_p + 4) = make_float4(o[4], o[5], o[6], o[7]);
}

DEV void dxsum_body(const bf16* __restrict__ vpT, const float* __restrict__ ob,
                    float* __restrict__ out, int blk) {
  int row = blk * 8 + (threadIdx.x >> 5);
  int tx = threadIdx.x & 31;
  float s[8] = {};
#pragma unroll
  for (int vd = 0; vd < 8; ++vd) {
    sh8 vv; vv.v = *(const short8*)&vpT[((size_t)(row * 8 + vd)) * 1024 + tx * 8];
#pragma unroll
    for (int c = 0; c < 8; ++c) s[c] += toF(vv.x[c]);
  }
  float4 o2a = *(const float4*)&ob[(size_t)row * 768 + 256 + tx * 8];
  float4 o2b = *(const float4*)&ob[(size_t)row * 768 + 260 + tx * 8];
  float4 o3a = *(const float4*)&ob[(size_t)row * 768 + 512 + tx * 8];
  float4 o3b = *(const float4*)&ob[(size_t)row * 768 + 516 + tx * 8];
  float o2[8] = {o2a.x, o2a.y, o2a.z, o2a.w, o2b.x, o2b.y, o2b.z, o2b.w};
  float o3[8] = {o3a.x, o3a.y, o3a.z, o3a.w, o3b.x, o3b.y, o3b.z, o3b.w};
  float r[8];
#pragma unroll
  for (int c = 0; c < 8; ++c) r[c] = s[c] * o2[c] + o3[c];
  float* dp = &out[(size_t)row * 256 + tx * 8];
  *(float4*)dp = make_float4(r[0], r[1], r[2], r[3]);
  *(float4*)(dp + 4) = make_float4(r[4], r[5], r[6], r[7]);
}

DEV void dvec_body(const bf16* __restrict__ vec_bf, const bf16* __restrict__ s12,
                   const float* __restrict__ d_ij, const int* __restrict__ ei,
                   const int* __restrict__ rowptr, const int* __restrict__ eids,
                   const bf16* __restrict__ vpT, const float* __restrict__ ob,
                   float* __restrict__ out, int n) {
  int tv = threadIdx.x >> 5, tx = threadIdx.x & 31;
  float acc[8] = {};
  int lo = rowptr[n], hi = rowptr[n + 1];
  for (int i = lo; i < hi; ++i) {
    int e = eids[i];
    int src = ei[e];
    sh8 s1, s2, vv;
    s1.v = *(const short8*)&s12[(size_t)e * 512 + tx * 8];
    s2.v = *(const short8*)&s12[(size_t)e * 512 + 256 + tx * 8];
    vv.v = *(const short8*)&vec_bf[((size_t)(src * 8 + tv)) * 256 + tx * 8];
    float dd = d_ij[e * 8 + tv];
#pragma unroll
    for (int c = 0; c < 8; ++c)
      acc[c] += toF(vv.x[c]) * toF(s1.x[c]) + toF(s2.x[c]) * dd;
  }
  sh8 v3; v3.v = *(const short8*)&vpT[((size_t)(n * 8 + tv)) * 1024 + 256 + tx * 8];
  float4 o1a = *(const float4*)&ob[(size_t)n * 768 + tx * 8];
  float4 o1b = *(const float4*)&ob[(size_t)n * 768 + 4 + tx * 8];
  float o1[8] = {o1a.x, o1a.y, o1a.z, o1a.w, o1b.x, o1b.y, o1b.z, o1b.w};
  float r[8];
#pragma unroll
  for (int c = 0; c < 8; ++c) r[c] = toF(v3.x[c]) * o1[c] + acc[c];
  float* dp = &out[((size_t)(n * 8 + tv)) * 256 + tx * 8];
  *(float4*)dp = make_float4(r[0], r[1], r[2], r[3]);
  *(float4*)(dp + 4) = make_float4(r[4], r[5], r[6], r[7]);
}

// ================= fused kernels =================

// ---- stage 1: csr | wprep x11 | cvt2 | ln ----
struct PrepArgs {
  const int* ei; int* rowptr; int* eids;
  WDesc wd[11];
  const float* f_ij; bf16* f_bf;
  const float* vec; bf16* vec_bf;
  const float* x; const float* ln_w; const float* ln_b; bf16* xn;
};

__global__ __launch_bounds__(256) void prep_k(PrepArgs a) {
  __shared__ __align__(16) char smem[25600];
  int blk = blockIdx.x;
  if (blk == 0) { csr_body(a.ei, a.rowptr, a.eids, (int*)smem); return; }
  blk -= 1;
  if (blk < 2112) { wprep_body(a.wd[blk / 192], (blk % 192) / 8, blk % 8, (float*)smem); return; }
  blk -= 2112;
  if (blk < 8192) {
    if (blk < 4096) cvt_body(a.f_ij, a.f_bf, blk);
    else cvt_body(a.vec, a.vec_bf, blk - 4096);
    return;
  }
  blk -= 8192;
  ln_body(a.x, a.ln_w, a.ln_b, a.xn, blk, (float*)smem);
}

// ---- stage 2: qkv GEMM | vpT GEMM ----
struct G2Args {
  const bf16 *xn, *Wqkv, *vecbf, *Wvt;
  bf16 *qkv, *vpT;
};
__global__ __launch_bounds__(256) void gemm2_k(G2Args a) {
  __shared__ __align__(16) char smem[16384];
  bf16* Als = (bf16*)smem; bf16* Bls = (bf16*)(smem + 8192);
  int id = blockIdx.x;
  if (id < 96)
    mgemm_body<0, bf16>(a.xn, a.Wqkv, nullptr, a.qkv, BNc, Hc, 768,
                        (id % 16) * 128, (id / 16) * 128, Als, Bls);
  else {
    id -= 96;
    mgemm_body<0, bf16>(a.vecbf, a.Wvt, nullptr, a.vpT, Ec, Hc, 1024,
                        (id % 128) * 128, (id / 128) * 128, Als, Bls);
  }
}

// ---- stage 3: MFMA attention (unchanged) ----
__global__ __launch_bounds__(256) void attn_mfma_k(
    const bf16* __restrict__ qkv, bf16* __restrict__ ob) {
  constexpr int QS = 768;
  int b = blockIdx.x >> 3, h = blockIdx.x & 7;
  int tid = threadIdx.x, lane = tid & 63, w = tid >> 6;
  int fm = lane & 15, g = lane >> 4;
  __shared__ bf16 Vt[32][264];
  __shared__ bf16 Ps[4][64][72];
  const bf16* qb = qkv + (size_t)b * 256 * QS + h * 32;
  const bf16* kb = qb + 256;
  const bf16* vb = qb + 512;
#pragma unroll
  for (int c = 0; c < 4; ++c) {
    int chunk = c * 256 + tid;
    int j = chunk >> 2, part = chunk & 3;
    sh8 t;
    t.v = *(const short8*)(vb + (size_t)j * QS + part * 8);
#pragma unroll
    for (int i = 0; i < 8; ++i) Vt[part * 8 + i][j] = t.x[i];
  }
  __syncthreads();
  short8 af[4];
#pragma unroll
  for (int mi = 0; mi < 4; ++mi)
    af[mi] = *(const short8*)(qb + (size_t)(w * 64 + mi * 16 + fm) * QS + g * 8);
  floatx4 oacc[4][2] = {};
  for (int jt = 0; jt < 4; ++jt) {
#pragma unroll
    for (int ni = 0; ni < 4; ++ni) {
      short8 bg = *(const short8*)(kb + (size_t)(jt * 64 + ni * 16 + fm) * QS + g * 8);
#pragma unroll
      for (int mi = 0; mi < 4; ++mi) {
        floatx4 z = {0.f, 0.f, 0.f, 0.f};
        floatx4 s = __builtin_amdgcn_mfma_f32_16x16x32_bf16(af[mi], bg, z, 0, 0, 0);
#pragma unroll
        for (int r = 0; r < 4; ++r) {
          float v = silu_f(s[r] * 0.17677669529663687f);
          Ps[w][mi * 16 + g * 4 + r][ni * 16 + fm] = __float2bfloat16(v);
        }
      }
    }
#pragma unroll
    for (int kt = 0; kt < 2; ++kt) {
      short8 bv0 = *(const short8*)&Vt[fm][jt * 64 + kt * 32 + g * 8];
      short8 bv1 = *(const short8*)&Vt[16 + fm][jt * 64 + kt * 32 + g * 8];
#pragma unroll
      for (int mi = 0; mi < 4; ++mi) {
        short8 ap = *(const short8*)&Ps[w][mi * 16 + fm][kt * 32 + g * 8];
        oacc[mi][0] = __builtin_amdgcn_mfma_f32_16x16x32_bf16(ap, bv0, oacc[mi][0], 0, 0, 0);
        oacc[mi][1] = __builtin_amdgcn_mfma_f32_16x16x32_bf16(ap, bv1, oacc[mi][1], 0, 0, 0);
      }
    }
  }
#pragma unroll
  for (int mi = 0; mi < 4; ++mi)
#pragma unroll
    for (int ni = 0; ni < 2; ++ni)
#pragma unroll
      for (int r = 0; r < 4; ++r) {
        int row = w * 64 + mi * 16 + g * 4 + r;
        int d = ni * 16 + fm;
        ob[((size_t)(b * 256 + row)) * 256 + h * 32 + d] =
            __float2bfloat16(oacc[mi][ni][r] * (1.0f / 256.0f));
      }
}

// ---- stage 4: Wao GEMM ----
template <int ACT, typename TC>
__global__ __launch_bounds__(256) void mgemm_k(
    const bf16* __restrict__ A, const bf16* __restrict__ Bt,
    const float* __restrict__ bias, TC* __restrict__ C,
    int M, int K, int N) {
  __shared__ __align__(16) char smem[16384];
  mgemm_body<ACT, TC>(A, Bt, bias, C, M, K, N,
                      blockIdx.x * 128, blockIdx.y * 128,
                      (bf16*)smem, (bf16*)(smem + 8192));
}

// ---- stage 5: dv|fW GEMM + fused vj epilogue ----
__global__ __launch_bounds__(256) void gemm_dvfw_k(
    const bf16* __restrict__ A, const bf16* __restrict__ Bt,
    const float* __restrict__ bdv, const float* __restrict__ bf_,
    const int* __restrict__ ei, const float* __restrict__ r_ij,
    const float* __restrict__ vbuf,
    bf16* __restrict__ vj, bf16* __restrict__ fW) {
  constexpr int K = 256;
  __shared__ __align__(16) char smem[16384];
  bf16* Als = (bf16*)smem; bf16* Bls = (bf16*)(smem + 8192);
  int tid = threadIdx.x;
  int lane = tid & 63, w = tid >> 6;
  int m0 = blockIdx.x * 128, n0 = blockIdx.y * 128;
  int wm = (w & 1) * 64, wn = (w >> 1) * 64;
  int fm = lane & 15, g = lane >> 4;
  floatx4 acc[4][4] = {};
  for (int k0 = 0; k0 < K; k0 += 32) {
#pragma unroll
    for (int t = 0; t < 2; ++t) {
      int c = t * 256 + w * 64 + lane;
      int r = c >> 2, q = c & 3;
      bf16* ldsA = &Als[(t * 256 + w * 64) * 8 + lane * 8];
      bf16* ldsB = &Bls[(t * 256 + w * 64) * 8 + lane * 8];
      async_copy16(A + (size_t)(m0 + r) * K + k0 + q * 8, ldsA);
      async_copy16(Bt + (size_t)(n0 + r) * K + k0 + q * 8, ldsB);
    }
    __syncthreads();
    short8 af[4], bg[4];
#pragma unroll
    for (int i = 0; i < 4; ++i) {
      af[i] = *(const short8*)&Als[(wm + i * 16 + fm) * 32 + g * 8];
      bg[i] = *(const short8*)&Bls[(wn + i * 16 + fm) * 32 + g * 8];
    }
#pragma unroll
    for (int mi = 0; mi < 4; ++mi)
#pragma unroll
      for (int ni = 0; ni < 4; ++ni)
        acc[mi][ni] = __builtin_amdgcn_mfma_f32_16x16x32_bf16(
            af[mi], bg[ni], acc[mi][ni], 0, 0, 0);
    __syncthreads();
  }
  bool isVj = (n0 < 256);
#pragma unroll
  for (int mi = 0; mi < 4; ++mi) {
    int row0 = m0 + wm + mi * 16 + g * 4;
#pragma unroll
    for (int r = 0; r < 4; ++r) {
      int e = row0 + r;
      int src = 0; float cut = 0.f;
      if (isVj) {
        src = ei[e];
        float rr = r_ij[e];
        cut = (rr < 5.0f) ? 0.5f * (cosf(0.6283185307179586f * rr) + 1.0f) : 0.0f;
      }
#pragma unroll
      for (int ni = 0; ni < 4; ++ni) {
        int col = n0 + wn + ni * 16 + fm;
        if (isVj) {
          float v = silu_f(acc[mi][ni][r] + bdv[col]);
          vj[(size_t)e * 256 + col] =
              __float2bfloat16(vbuf[(size_t)src * 256 + col] * cut * v);
        } else {
          float v = silu_f(acc[mi][ni][r] + bf_[col - 256]);
          fW[(size_t)e * 256 + (col - 256)] = __float2bfloat16(v);
        }
      }
    }
  }
}

// ---- stage 6: s12 GEMM | xagg ----
struct S6Args {
  const bf16 *vj, *Ws_t; const float* bs; bf16* s12;
  const int *rowptr, *eids; bf16* xagg;
};
__global__ __launch_bounds__(256) void stage6_k(S6Args a) {
  __shared__ __align__(16) char smem[16384];
  int id = blockIdx.x;
  if (id < 512)
    mgemm_body<1, bf16>(a.vj, a.Ws_t, a.bs, a.s12, Ec, Hc, 512,
                        (id % 128) * 128, (id / 128) * 128,
                        (bf16*)smem, (bf16*)(smem + 8192));
  else
    xagg_body(a.vj, a.rowptr, a.eids, a.xagg, id - 512);
}

// ---- stage 7: Wo GEMM | df ----
struct S7Args {
  const bf16 *xagg, *Wo_t; const float* bo; float* obuf;
  const bf16* vpT; const float* d_ij; const bf16* fW;
  const int* ei; float* out_df;
};
__global__ __launch_bounds__(256) void stage7_k(S7Args a) {
  __shared__ __align__(16) char smem[16384];
  int id = blockIdx.x;
  if (id < 96)
    mgemm_body<0, float>(a.xagg, a.Wo_t, a.bo, a.obuf, BNc, Hc, 768,
                         (id % 16) * 128, (id / 16) * 128,
                         (bf16*)smem, (bf16*)(smem + 8192));
  else
    df_body(a.vpT, a.d_ij, a.fW, a.ei, a.out_df, id - 96);
}

// ---- stage 8: dxsum | dvec_agg ----
struct S8Args {
  const bf16* vpT; const float* obuf; float* out_dx;
  const bf16 *vecbf, *s12; const float* d_ij;
  const int *ei, *rowptr, *eids; float* out_dvec;
};
__global__ __launch_bounds__(256) void stage8_k(S8Args a) {
  int id = blockIdx.x;
  if (id < 256)
    dxsum_body(a.vpT, a.obuf, a.out_dx, id);
  else
    dvec_body(a.vecbf, a.s12, a.d_ij, a.ei, a.rowptr, a.eids,
              a.vpT, a.obuf, a.out_dvec, id - 256);
}

extern "C" void kernel_launch(void* const* d_in, const int* in_sizes, int n_in,
                              void* d_out, int out_size, void* d_ws, size_t ws_size,
                              hipStream_t stream) {
  const float* x    = (const float*)d_in[0];
  const float* vec  = (const float*)d_in[1];
  const int*   ei   = (const int*)d_in[2];
  const float* r_ij = (const float*)d_in[3];
  const float* f_ij = (const float*)d_in[4];
  const float* d_ij = (const float*)d_in[5];
  const float* ln_w = (const float*)d_in[7];
  const float* ln_b = (const float*)d_in[8];
  const float* Wq   = (const float*)d_in[9];
  const float* Wk   = (const float*)d_in[10];
  const float* Wv   = (const float*)d_in[11];
  const float* Wao  = (const float*)d_in[12];
  const float* Wvec = (const float*)d_in[13];
  const float* Wdv  = (const float*)d_in[14];
  const float* bdv  = (const float*)d_in[15];
  const float* Ws   = (const float*)d_in[16];
  const float* bs   = (const float*)d_in[17];
  const float* Wo   = (const float*)d_in[18];
  const float* bo   = (const float*)d_in[19];
  const float* Wf   = (const float*)d_in[20];
  const float* bf_  = (const float*)d_in[21];
  const float* Wsrc = (const float*)d_in[22];
  const float* Wtrg = (const float*)d_in[23];

  char* p = (char*)d_ws;
  auto alloc = [&](size_t bytes) {
    char* r = p; p += (bytes + 255) & ~(size_t)255; return r;
  };
  bf16*  xn_bf   = (bf16*)alloc((size_t)BNc * Hc * 2);
  bf16*  qkv_bf  = (bf16*)alloc((size_t)BNc * 3 * Hc * 2);
  bf16*  attn_bf = (bf16*)alloc((size_t)BNc * Hc * 2);
  float* vbuf    = (float*)alloc((size_t)BNc * Hc * 4);
  bf16*  xagg_bf = (bf16*)alloc((size_t)BNc * Hc * 2);
  float* obuf    = (float*)alloc((size_t)BNc * 3 * Hc * 4);
  bf16*  f_bf    = (bf16*)alloc((size_t)Ec * Hc * 2);
  bf16*  vec_bf  = (bf16*)alloc((size_t)BNc * VDc * Hc * 2);
  bf16*  vpT     = (bf16*)alloc((size_t)Ec * 1024 * 2);     // v1|v3|Tt|Ts
  bf16*  vj_bf   = (bf16*)alloc((size_t)Ec * Hc * 2);
  bf16*  s12_bf  = (bf16*)alloc((size_t)Ec * 2 * Hc * 2);
  bf16*  fW_bf   = (bf16*)alloc((size_t)Ec * Hc * 2);
  bf16*  Wqkv_t  = (bf16*)alloc((size_t)3 * Hc * Hc * 2);
  bf16*  Wao_t   = (bf16*)alloc((size_t)Hc * Hc * 2);
  bf16*  Wdvf_t  = (bf16*)alloc((size_t)2 * Hc * Hc * 2);
  bf16*  Wvt_t   = (bf16*)alloc((size_t)4 * Hc * Hc * 2);
  bf16*  Ws_t    = (bf16*)alloc((size_t)2 * Hc * Hc * 2);
  bf16*  Wo_t    = (bf16*)alloc((size_t)3 * Hc * Hc * 2);
  int*   rowptr  = (int*)alloc(2049 * 4);
  int*   eids    = (int*)alloc(Ec * 4);

  float* out_dx   = (float*)d_out;
  float* out_dvec = (float*)d_out + 524288;
  float* out_df   = (float*)d_out + 4718592;

  // stage 1: csr | wprep | cvt2 | ln  (1 + 2112 + 8192 + 2048 blocks)
  PrepArgs pa;
  pa.ei = ei; pa.rowptr = rowptr; pa.eids = eids;
  pa.wd[0]  = {Wq,   Wqkv_t,           Hc, Hc};
  pa.wd[1]  = {Wk,   Wqkv_t + 65536,   Hc, Hc};
  pa.wd[2]  = {Wv,   Wqkv_t + 131072,  Hc, Hc};
  pa.wd[3]  = {Wao,  Wao_t,            Hc, Hc};
  pa.wd[4]  = {Wdv,  Wdvf_t,           Hc, Hc};
  pa.wd[5]  = {Wf,   Wdvf_t + 65536,   Hc, Hc};
  pa.wd[6]  = {Wvec, Wvt_t,            Hc, 2 * Hc};
  pa.wd[7]  = {Wtrg, Wvt_t + 131072,   Hc, Hc};
  pa.wd[8]  = {Wsrc, Wvt_t + 196608,   Hc, Hc};
  pa.wd[9]  = {Ws,   Ws_t,             Hc, 2 * Hc};
  pa.wd[10] = {Wo,   Wo_t,             Hc, 3 * Hc};
  pa.f_ij = f_ij; pa.f_bf = f_bf; pa.vec = vec; pa.vec_bf = vec_bf;
  pa.x = x; pa.ln_w = ln_w; pa.ln_b = ln_b; pa.xn = xn_bf;
  prep_k<<<12353, 256, 0, stream>>>(pa);

  // stage 2: qkv | vpT GEMMs (96 + 1024 tiles)
  G2Args g2{xn_bf, Wqkv_t, vec_bf, Wvt_t, qkv_bf, vpT};
  gemm2_k<<<1120, 256, 0, stream>>>(g2);

  // stage 3: attention
  attn_mfma_k<<<Bc * NHc, 256, 0, stream>>>(qkv_bf, attn_bf);

  // stage 4: v = attn @ Wao
  mgemm_k<0, float><<<dim3(16, 2), 256, 0, stream>>>(attn_bf, Wao_t, nullptr, vbuf, BNc, Hc, Hc);

  // stage 5: dv|fW GEMM + vj epilogue
  gemm_dvfw_k<<<dim3(128, 4), 256, 0, stream>>>(f_bf, Wdvf_t, bdv, bf_, ei, r_ij,
                                                vbuf, vj_bf, fW_bf);

  // stage 6: s12 GEMM | xagg (512 + 256)
  S6Args s6{vj_bf, Ws_t, bs, s12_bf, rowptr, eids, xagg_bf};
  stage6_k<<<768, 256, 0, stream>>>(s6);

  // stage 7: Wo GEMM | df (96 + 2048)
  S7Args s7{xagg_bf, Wo_t, bo, obuf, vpT, d_ij, fW_bf, ei, out_df};
  stage7_k<<<2144, 256, 0, stream>>>(s7);

  // stage 8: dxsum | dvec_agg (256 + 2048)
  S8Args s8{vpT, obuf, out_dx, vec_bf, s12_bf, d_ij, ei, rowptr, eids, out_dvec};
  stage8_k<<<2304, 256, 0, stream>>>(s8);

  (void)in_sizes; (void)n_in; (void)out_size; (void)ws_size;
}

// Round 8
// 277.582 us; speedup vs baseline: 2.7215x; 1.0902x over previous
//
#include <hip/hip_runtime.h>
#include <hip/hip_bf16.h>
#include <math.h>

typedef __hip_bfloat16 bf16;
#define DEV __device__ __forceinline__
DEV float silu_f(float x) { return x / (1.0f + __expf(-x)); }
DEV float toF(bf16 x) { return __bfloat162float(x); }
DEV void storeF(float* p, float v) { *p = v; }
DEV void storeF(bf16* p, float v) { *p = __float2bfloat16(v); }

constexpr int Bc = 8, Nc = 256, BNc = 2048, Ec = 16384;
constexpr int Hc = 256, NHc = 8, HDc = 32, VDc = 8;

typedef __attribute__((ext_vector_type(8))) short short8;
typedef __attribute__((ext_vector_type(4))) float floatx4;
union sh8 { short8 v; bf16 x[8]; };

DEV void async_copy16(const void* g, void* l) {
  __builtin_amdgcn_global_load_lds(
      (const __attribute__((address_space(1))) void*)g,
      (__attribute__((address_space(3))) void*)l, 16, 0, 0);
}

// ================= device bodies =================

// ---- CSR build (single block, 256 threads, vectorized int4 loads) ----
// Throughput-bound rework: dst[] is read as int4 (8 outstanding 16B loads per
// round), histogram/fill via LDS atomics. Old scalar version serialized 64
// dependent global loads -> ~50us straggler block (R7 counters).
DEV void csr_body(const int* __restrict__ ei, int* __restrict__ rowptr,
                  int* __restrict__ eids, int* sm) {
  int* deg = sm;         // 2048
  int* cur = sm + 2048;  // 2048
  int* rp  = sm + 4096;  // 2048
  int* ps  = sm + 6144;  // 256
  int t = threadIdx.x;
  for (int i = t; i < 2048; i += 256) { deg[i] = 0; cur[i] = 0; }
  __syncthreads();
  // histogram: 16384 dst ints = 4096 int4, 16 per thread, in 2 rounds of 8
#pragma unroll
  for (int rr = 0; rr < 2; ++rr) {
    int4 dv[8];
#pragma unroll
    for (int i = 0; i < 8; ++i)
      dv[i] = *(const int4*)&ei[Ec + ((rr * 8 + i) * 256 + t) * 4];
#pragma unroll
    for (int i = 0; i < 8; ++i) {
      atomicAdd(&deg[dv[i].x], 1); atomicAdd(&deg[dv[i].y], 1);
      atomicAdd(&deg[dv[i].z], 1); atomicAdd(&deg[dv[i].w], 1);
    }
  }
  __syncthreads();
  int loc[8], s = 0;
#pragma unroll
  for (int i = 0; i < 8; ++i) { loc[i] = s; s += deg[t * 8 + i]; }
  ps[t] = s;
  __syncthreads();
  for (int off = 1; off < 256; off <<= 1) {
    int v = (t >= off) ? ps[t - off] : 0;
    __syncthreads();
    ps[t] += v;
    __syncthreads();
  }
  int base = (t == 0) ? 0 : ps[t - 1];
#pragma unroll
  for (int i = 0; i < 8; ++i) {
    rp[t * 8 + i] = base + loc[i];
    rowptr[t * 8 + i] = base + loc[i];
  }
  if (t == 255) rowptr[2048] = Ec;
  __syncthreads();
  // fill: re-load dst (L2-hot), LDS cursor atomics, scatter eids
#pragma unroll
  for (int rr = 0; rr < 2; ++rr) {
    int4 dv[8];
#pragma unroll
    for (int i = 0; i < 8; ++i)
      dv[i] = *(const int4*)&ei[Ec + ((rr * 8 + i) * 256 + t) * 4];
#pragma unroll
    for (int i = 0; i < 8; ++i) {
      int e0 = ((rr * 8 + i) * 256 + t) * 4;
      int p0 = atomicAdd(&cur[dv[i].x], 1); eids[rp[dv[i].x] + p0] = e0;
      int p1 = atomicAdd(&cur[dv[i].y], 1); eids[rp[dv[i].y] + p1] = e0 + 1;
      int p2 = atomicAdd(&cur[dv[i].z], 1); eids[rp[dv[i].z] + p2] = e0 + 2;
      int p3 = atomicAdd(&cur[dv[i].w], 1); eids[rp[dv[i].w] + p3] = e0 + 3;
    }
  }
}

// ---- weight transpose+cvt ----
struct WDesc { const float* in; bf16* out; int K, N; };

DEV void wprep_body(WDesc wd, int by, int bx, float* sm) {
  if (by * 32 >= wd.N) return;
  float (*t)[33] = (float (*)[33])sm;
  int k0 = bx * 32, n0 = by * 32;
  int tx = threadIdx.x & 31, ty = threadIdx.x >> 5;
#pragma unroll
  for (int i = 0; i < 32; i += 8)
    t[ty + i][tx] = wd.in[(size_t)(k0 + ty + i) * wd.N + n0 + tx];
  __syncthreads();
#pragma unroll
  for (int i = 0; i < 32; i += 8)
    wd.out[(size_t)(n0 + ty + i) * wd.K + k0 + tx] = __float2bfloat16(t[tx][ty + i]);
}

// ---- fp32 -> bf16 ----
DEV void cvt_body(const float* __restrict__ in, bf16* __restrict__ out, int blk) {
  int i = (blk * 256 + threadIdx.x) * 4;
  float4 v = *(const float4*)&in[i];
  union { bf16 x[4]; uint2 u; } o;
  o.x[0] = __float2bfloat16(v.x); o.x[1] = __float2bfloat16(v.y);
  o.x[2] = __float2bfloat16(v.z); o.x[3] = __float2bfloat16(v.w);
  *(uint2*)&out[i] = o.u;
}

// ---- LayerNorm ----
DEV void ln_body(const float* __restrict__ x, const float* __restrict__ w,
                 const float* __restrict__ b, bf16* __restrict__ xn,
                 int row, float* sm) {
  int h = threadIdx.x;
  float v = x[(size_t)row * Hc + h];
  sm[h] = v; __syncthreads();
  for (int s = 128; s > 0; s >>= 1) { if (h < s) sm[h] += sm[h + s]; __syncthreads(); }
  float mu = sm[0] * (1.0f / 256.0f);
  __syncthreads();
  float d = v - mu;
  sm[h] = d * d; __syncthreads();
  for (int s = 128; s > 0; s >>= 1) { if (h < s) sm[h] += sm[h + s]; __syncthreads(); }
  float var = sm[0] * (1.0f / 256.0f);
  float r = rsqrtf(var + 1e-5f);
  xn[(size_t)row * Hc + h] = __float2bfloat16(d * r * w[h] + b[h]);
}

// ---- MFMA GEMM tile body ----
template <int ACT, typename TC>
DEV void mgemm_body(const bf16* __restrict__ A, const bf16* __restrict__ Bt,
                    const float* __restrict__ bias, TC* __restrict__ C,
                    int M, int K, int N, int m0, int n0,
                    bf16* Als, bf16* Bls) {
  int tid = threadIdx.x;
  int lane = tid & 63, w = tid >> 6;
  int wm = (w & 1) * 64, wn = (w >> 1) * 64;
  int fm = lane & 15, g = lane >> 4;
  floatx4 acc[4][4] = {};
  for (int k0 = 0; k0 < K; k0 += 32) {
#pragma unroll
    for (int t = 0; t < 2; ++t) {
      int c = t * 256 + w * 64 + lane;
      int r = c >> 2, q = c & 3;
      bf16* ldsA = &Als[(t * 256 + w * 64) * 8 + lane * 8];
      bf16* ldsB = &Bls[(t * 256 + w * 64) * 8 + lane * 8];
      async_copy16(A + (size_t)(m0 + r) * K + k0 + q * 8, ldsA);
      async_copy16(Bt + (size_t)(n0 + r) * K + k0 + q * 8, ldsB);
    }
    __syncthreads();
    short8 af[4], bg[4];
#pragma unroll
    for (int i = 0; i < 4; ++i) {
      af[i] = *(const short8*)&Als[(wm + i * 16 + fm) * 32 + g * 8];
      bg[i] = *(const short8*)&Bls[(wn + i * 16 + fm) * 32 + g * 8];
    }
#pragma unroll
    for (int mi = 0; mi < 4; ++mi)
#pragma unroll
      for (int ni = 0; ni < 4; ++ni)
        acc[mi][ni] = __builtin_amdgcn_mfma_f32_16x16x32_bf16(
            af[mi], bg[ni], acc[mi][ni], 0, 0, 0);
    __syncthreads();
  }
#pragma unroll
  for (int mi = 0; mi < 4; ++mi) {
    int row0 = m0 + wm + mi * 16 + g * 4;
#pragma unroll
    for (int ni = 0; ni < 4; ++ni) {
      int col = n0 + wn + ni * 16 + fm;
      float bv = bias ? bias[col] : 0.0f;
#pragma unroll
      for (int r = 0; r < 4; ++r) {
        float v = acc[mi][ni][r] + bv;
        if (ACT) v = silu_f(v);
        storeF(&C[(size_t)(row0 + r) * N + col], v);
      }
    }
  }
}

// ---- vectorized gather bodies (8 cols / thread, short8 loads) ----
DEV void xagg_body(const bf16* __restrict__ vj, const int* __restrict__ rowptr,
                   const int* __restrict__ eids, bf16* __restrict__ xagg, int blk) {
  int node = blk * 8 + (threadIdx.x >> 5);
  int tx = threadIdx.x & 31;
  float acc[8] = {};
  int lo = rowptr[node], hi = rowptr[node + 1];
  for (int i = lo; i < hi; ++i) {
    sh8 vv; vv.v = *(const short8*)&vj[(size_t)eids[i] * 256 + tx * 8];
#pragma unroll
    for (int c = 0; c < 8; ++c) acc[c] += toF(vv.x[c]);
  }
  sh8 o;
#pragma unroll
  for (int c = 0; c < 8; ++c) o.x[c] = __float2bfloat16(acc[c]);
  *(short8*)&xagg[(size_t)node * 256 + tx * 8] = o.v;
}

DEV void df_body(const bf16* __restrict__ vpT, const float* __restrict__ d_ij,
                 const bf16* __restrict__ fW, const int* __restrict__ ei,
                 float* __restrict__ out, int blk) {
  int te = threadIdx.x >> 5, tx = threadIdx.x & 31;
  int e = blk * 8 + te;
  int src = ei[e], dst = ei[Ec + e];
  float S[8] = {}, p1[8] = {}, p2[8] = {};
#pragma unroll
  for (int vd = 0; vd < 8; ++vd) {
    sh8 t1, t2;
    t1.v = *(const short8*)&vpT[((size_t)(dst * 8 + vd)) * 1024 + 512 + tx * 8];
    t2.v = *(const short8*)&vpT[((size_t)(src * 8 + vd)) * 1024 + 768 + tx * 8];
    float dd = d_ij[e * 8 + vd];
#pragma unroll
    for (int c = 0; c < 8; ++c) {
      float a = toF(t1.x[c]), b = toF(t2.x[c]);
      S[c] += a * b; p1[c] += a * dd; p2[c] += b * dd;
    }
  }
  sh8 fw; fw.v = *(const short8*)&fW[(size_t)e * 256 + tx * 8];
  float o[8];
#pragma unroll
  for (int c = 0; c < 8; ++c) o[c] = toF(fw.x[c]) * (S[c] - p1[c] * p2[c]);
  float* dst_p = &out[(size_t)e * 256 + tx * 8];
  *(float4*)dst_p = make_float4(o[0], o[1], o[2], o[3]);
  *(float4*)(dst_p + 4) = make_float4(o[4], o[5], o[6], o[7]);
}

DEV void dxsum_body(const bf16* __restrict__ vpT, const float* __restrict__ ob,
                    float* __restrict__ out, int blk) {
  int row = blk * 8 + (threadIdx.x >> 5);
  int tx = threadIdx.x & 31;
  float s[8] = {};
#pragma unroll
  for (int vd = 0; vd < 8; ++vd) {
    sh8 vv; vv.v = *(const short8*)&vpT[((size_t)(row * 8 + vd)) * 1024 + tx * 8];
#pragma unroll
    for (int c = 0; c < 8; ++c) s[c] += toF(vv.x[c]);
  }
  float4 o2a = *(const float4*)&ob[(size_t)row * 768 + 256 + tx * 8];
  float4 o2b = *(const float4*)&ob[(size_t)row * 768 + 260 + tx * 8];
  float4 o3a = *(const float4*)&ob[(size_t)row * 768 + 512 + tx * 8];
  float4 o3b = *(const float4*)&ob[(size_t)row * 768 + 516 + tx * 8];
  float o2[8] = {o2a.x, o2a.y, o2a.z, o2a.w, o2b.x, o2b.y, o2b.z, o2b.w};
  float o3[8] = {o3a.x, o3a.y, o3a.z, o3a.w, o3b.x, o3b.y, o3b.z, o3b.w};
  float r[8];
#pragma unroll
  for (int c = 0; c < 8; ++c) r[c] = s[c] * o2[c] + o3[c];
  float* dp = &out[(size_t)row * 256 + tx * 8];
  *(float4*)dp = make_float4(r[0], r[1], r[2], r[3]);
  *(float4*)(dp + 4) = make_float4(r[4], r[5], r[6], r[7]);
}

DEV void dvec_body(const bf16* __restrict__ vec_bf, const bf16* __restrict__ s12,
                   const float* __restrict__ d_ij, const int* __restrict__ ei,
                   const int* __restrict__ rowptr, const int* __restrict__ eids,
                   const bf16* __restrict__ vpT, const float* __restrict__ ob,
                   float* __restrict__ out, int n) {
  int tv = threadIdx.x >> 5, tx = threadIdx.x & 31;
  float acc[8] = {};
  int lo = rowptr[n], hi = rowptr[n + 1];
  for (int i = lo; i < hi; ++i) {
    int e = eids[i];
    int src = ei[e];
    sh8 s1, s2, vv;
    s1.v = *(const short8*)&s12[(size_t)e * 512 + tx * 8];
    s2.v = *(const short8*)&s12[(size_t)e * 512 + 256 + tx * 8];
    vv.v = *(const short8*)&vec_bf[((size_t)(src * 8 + tv)) * 256 + tx * 8];
    float dd = d_ij[e * 8 + tv];
#pragma unroll
    for (int c = 0; c < 8; ++c)
      acc[c] += toF(vv.x[c]) * toF(s1.x[c]) + toF(s2.x[c]) * dd;
  }
  sh8 v3; v3.v = *(const short8*)&vpT[((size_t)(n * 8 + tv)) * 1024 + 256 + tx * 8];
  float4 o1a = *(const float4*)&ob[(size_t)n * 768 + tx * 8];
  float4 o1b = *(const float4*)&ob[(size_t)n * 768 + 4 + tx * 8];
  float o1[8] = {o1a.x, o1a.y, o1a.z, o1a.w, o1b.x, o1b.y, o1b.z, o1b.w};
  float r[8];
#pragma unroll
  for (int c = 0; c < 8; ++c) r[c] = toF(v3.x[c]) * o1[c] + acc[c];
  float* dp = &out[((size_t)(n * 8 + tv)) * 256 + tx * 8];
  *(float4*)dp = make_float4(r[0], r[1], r[2], r[3]);
  *(float4*)(dp + 4) = make_float4(r[4], r[5], r[6], r[7]);
}

// ================= fused kernels =================

// ---- stage 1: csr | wprep x11 | cvt2 | ln ----
struct PrepArgs {
  const int* ei; int* rowptr; int* eids;
  WDesc wd[11];
  const float* f_ij; bf16* f_bf;
  const float* vec; bf16* vec_bf;
  const float* x; const float* ln_w; const float* ln_b; bf16* xn;
};

__global__ __launch_bounds__(256) void prep_k(PrepArgs a) {
  __shared__ __align__(16) char smem[25600];
  int blk = blockIdx.x;
  if (blk == 0) { csr_body(a.ei, a.rowptr, a.eids, (int*)smem); return; }
  blk -= 1;
  if (blk < 2112) { wprep_body(a.wd[blk / 192], (blk % 192) / 8, blk % 8, (float*)smem); return; }
  blk -= 2112;
  if (blk < 8192) {
    if (blk < 4096) cvt_body(a.f_ij, a.f_bf, blk);
    else cvt_body(a.vec, a.vec_bf, blk - 4096);
    return;
  }
  blk -= 8192;
  ln_body(a.x, a.ln_w, a.ln_b, a.xn, blk, (float*)smem);
}

// ---- stage 2: qkv GEMM | vpT GEMM ----
struct G2Args {
  const bf16 *xn, *Wqkv, *vecbf, *Wvt;
  bf16 *qkv, *vpT;
};
__global__ __launch_bounds__(256) void gemm2_k(G2Args a) {
  __shared__ __align__(16) char smem[16384];
  bf16* Als = (bf16*)smem; bf16* Bls = (bf16*)(smem + 8192);
  int id = blockIdx.x;
  if (id < 96)
    mgemm_body<0, bf16>(a.xn, a.Wqkv, nullptr, a.qkv, BNc, Hc, 768,
                        (id % 16) * 128, (id / 16) * 128, Als, Bls);
  else {
    id -= 96;
    mgemm_body<0, bf16>(a.vecbf, a.Wvt, nullptr, a.vpT, Ec, Hc, 1024,
                        (id % 128) * 128, (id / 128) * 128, Als, Bls);
  }
}

// ---- stage 3: MFMA attention ----
__global__ __launch_bounds__(256) void attn_mfma_k(
    const bf16* __restrict__ qkv, bf16* __restrict__ ob) {
  constexpr int QS = 768;
  int b = blockIdx.x >> 3, h = blockIdx.x & 7;
  int tid = threadIdx.x, lane = tid & 63, w = tid >> 6;
  int fm = lane & 15, g = lane >> 4;
  __shared__ bf16 Vt[32][264];
  __shared__ bf16 Ps[4][64][72];
  const bf16* qb = qkv + (size_t)b * 256 * QS + h * 32;
  const bf16* kb = qb + 256;
  const bf16* vb = qb + 512;
#pragma unroll
  for (int c = 0; c < 4; ++c) {
    int chunk = c * 256 + tid;
    int j = chunk >> 2, part = chunk & 3;
    sh8 t;
    t.v = *(const short8*)(vb + (size_t)j * QS + part * 8);
#pragma unroll
    for (int i = 0; i < 8; ++i) Vt[part * 8 + i][j] = t.x[i];
  }
  __syncthreads();
  short8 af[4];
#pragma unroll
  for (int mi = 0; mi < 4; ++mi)
    af[mi] = *(const short8*)(qb + (size_t)(w * 64 + mi * 16 + fm) * QS + g * 8);
  floatx4 oacc[4][2] = {};
  for (int jt = 0; jt < 4; ++jt) {
#pragma unroll
    for (int ni = 0; ni < 4; ++ni) {
      short8 bg = *(const short8*)(kb + (size_t)(jt * 64 + ni * 16 + fm) * QS + g * 8);
#pragma unroll
      for (int mi = 0; mi < 4; ++mi) {
        floatx4 z = {0.f, 0.f, 0.f, 0.f};
        floatx4 s = __builtin_amdgcn_mfma_f32_16x16x32_bf16(af[mi], bg, z, 0, 0, 0);
#pragma unroll
        for (int r = 0; r < 4; ++r) {
          float v = silu_f(s[r] * 0.17677669529663687f);
          Ps[w][mi * 16 + g * 4 + r][ni * 16 + fm] = __float2bfloat16(v);
        }
      }
    }
#pragma unroll
    for (int kt = 0; kt < 2; ++kt) {
      short8 bv0 = *(const short8*)&Vt[fm][jt * 64 + kt * 32 + g * 8];
      short8 bv1 = *(const short8*)&Vt[16 + fm][jt * 64 + kt * 32 + g * 8];
#pragma unroll
      for (int mi = 0; mi < 4; ++mi) {
        short8 ap = *(const short8*)&Ps[w][mi * 16 + fm][kt * 32 + g * 8];
        oacc[mi][0] = __builtin_amdgcn_mfma_f32_16x16x32_bf16(ap, bv0, oacc[mi][0], 0, 0, 0);
        oacc[mi][1] = __builtin_amdgcn_mfma_f32_16x16x32_bf16(ap, bv1, oacc[mi][1], 0, 0, 0);
      }
    }
  }
#pragma unroll
  for (int mi = 0; mi < 4; ++mi)
#pragma unroll
    for (int ni = 0; ni < 2; ++ni)
#pragma unroll
      for (int r = 0; r < 4; ++r) {
        int row = w * 64 + mi * 16 + g * 4 + r;
        int d = ni * 16 + fm;
        ob[((size_t)(b * 256 + row)) * 256 + h * 32 + d] =
            __float2bfloat16(oacc[mi][ni][r] * (1.0f / 256.0f));
      }
}

// ---- stage 4: Wao GEMM ----
template <int ACT, typename TC>
__global__ __launch_bounds__(256) void mgemm_k(
    const bf16* __restrict__ A, const bf16* __restrict__ Bt,
    const float* __restrict__ bias, TC* __restrict__ C,
    int M, int K, int N) {
  __shared__ __align__(16) char smem[16384];
  mgemm_body<ACT, TC>(A, Bt, bias, C, M, K, N,
                      blockIdx.x * 128, blockIdx.y * 128,
                      (bf16*)smem, (bf16*)(smem + 8192));
}

// ---- stage 5: dv|fW GEMM + fused vj epilogue ----
__global__ __launch_bounds__(256) void gemm_dvfw_k(
    const bf16* __restrict__ A, const bf16* __restrict__ Bt,
    const float* __restrict__ bdv, const float* __restrict__ bf_,
    const int* __restrict__ ei, const float* __restrict__ r_ij,
    const float* __restrict__ vbuf,
    bf16* __restrict__ vj, bf16* __restrict__ fW) {
  constexpr int K = 256;
  __shared__ __align__(16) char smem[16384];
  bf16* Als = (bf16*)smem; bf16* Bls = (bf16*)(smem + 8192);
  int tid = threadIdx.x;
  int lane = tid & 63, w = tid >> 6;
  int m0 = blockIdx.x * 128, n0 = blockIdx.y * 128;
  int wm = (w & 1) * 64, wn = (w >> 1) * 64;
  int fm = lane & 15, g = lane >> 4;
  floatx4 acc[4][4] = {};
  for (int k0 = 0; k0 < K; k0 += 32) {
#pragma unroll
    for (int t = 0; t < 2; ++t) {
      int c = t * 256 + w * 64 + lane;
      int r = c >> 2, q = c & 3;
      bf16* ldsA = &Als[(t * 256 + w * 64) * 8 + lane * 8];
      bf16* ldsB = &Bls[(t * 256 + w * 64) * 8 + lane * 8];
      async_copy16(A + (size_t)(m0 + r) * K + k0 + q * 8, ldsA);
      async_copy16(Bt + (size_t)(n0 + r) * K + k0 + q * 8, ldsB);
    }
    __syncthreads();
    short8 af[4], bg[4];
#pragma unroll
    for (int i = 0; i < 4; ++i) {
      af[i] = *(const short8*)&Als[(wm + i * 16 + fm) * 32 + g * 8];
      bg[i] = *(const short8*)&Bls[(wn + i * 16 + fm) * 32 + g * 8];
    }
#pragma unroll
    for (int mi = 0; mi < 4; ++mi)
#pragma unroll
      for (int ni = 0; ni < 4; ++ni)
        acc[mi][ni] = __builtin_amdgcn_mfma_f32_16x16x32_bf16(
            af[mi], bg[ni], acc[mi][ni], 0, 0, 0);
    __syncthreads();
  }
  bool isVj = (n0 < 256);
#pragma unroll
  for (int mi = 0; mi < 4; ++mi) {
    int row0 = m0 + wm + mi * 16 + g * 4;
#pragma unroll
    for (int r = 0; r < 4; ++r) {
      int e = row0 + r;
      int src = 0; float cut = 0.f;
      if (isVj) {
        src = ei[e];
        float rr = r_ij[e];
        cut = (rr < 5.0f) ? 0.5f * (cosf(0.6283185307179586f * rr) + 1.0f) : 0.0f;
      }
#pragma unroll
      for (int ni = 0; ni < 4; ++ni) {
        int col = n0 + wn + ni * 16 + fm;
        if (isVj) {
          float v = silu_f(acc[mi][ni][r] + bdv[col]);
          vj[(size_t)e * 256 + col] =
              __float2bfloat16(vbuf[(size_t)src * 256 + col] * cut * v);
        } else {
          float v = silu_f(acc[mi][ni][r] + bf_[col - 256]);
          fW[(size_t)e * 256 + (col - 256)] = __float2bfloat16(v);
        }
      }
    }
  }
}

// ---- stage 6: s12 GEMM | xagg ----
struct S6Args {
  const bf16 *vj, *Ws_t; const float* bs; bf16* s12;
  const int *rowptr, *eids; bf16* xagg;
};
__global__ __launch_bounds__(256) void stage6_k(S6Args a) {
  __shared__ __align__(16) char smem[16384];
  int id = blockIdx.x;
  if (id < 512)
    mgemm_body<1, bf16>(a.vj, a.Ws_t, a.bs, a.s12, Ec, Hc, 512,
                        (id % 128) * 128, (id / 128) * 128,
                        (bf16*)smem, (bf16*)(smem + 8192));
  else
    xagg_body(a.vj, a.rowptr, a.eids, a.xagg, id - 512);
}

// ---- stage 7: Wo GEMM | df ----
struct S7Args {
  const bf16 *xagg, *Wo_t; const float* bo; float* obuf;
  const bf16* vpT; const float* d_ij; const bf16* fW;
  const int* ei; float* out_df;
};
__global__ __launch_bounds__(256) void stage7_k(S7Args a) {
  __shared__ __align__(16) char smem[16384];
  int id = blockIdx.x;
  if (id < 96)
    mgemm_body<0, float>(a.xagg, a.Wo_t, a.bo, a.obuf, BNc, Hc, 768,
                         (id % 16) * 128, (id / 16) * 128,
                         (bf16*)smem, (bf16*)(smem + 8192));
  else
    df_body(a.vpT, a.d_ij, a.fW, a.ei, a.out_df, id - 96);
}

// ---- stage 8: dxsum | dvec_agg ----
struct S8Args {
  const bf16* vpT; const float* obuf; float* out_dx;
  const bf16 *vecbf, *s12; const float* d_ij;
  const int *ei, *rowptr, *eids; float* out_dvec;
};
__global__ __launch_bounds__(256) void stage8_k(S8Args a) {
  int id = blockIdx.x;
  if (id < 256)
    dxsum_body(a.vpT, a.obuf, a.out_dx, id);
  else
    dvec_body(a.vecbf, a.s12, a.d_ij, a.ei, a.rowptr, a.eids,
              a.vpT, a.obuf, a.out_dvec, id - 256);
}

extern "C" void kernel_launch(void* const* d_in, const int* in_sizes, int n_in,
                              void* d_out, int out_size, void* d_ws, size_t ws_size,
                              hipStream_t stream) {
  const float* x    = (const float*)d_in[0];
  const float* vec  = (const float*)d_in[1];
  const int*   ei   = (const int*)d_in[2];
  const float* r_ij = (const float*)d_in[3];
  const float* f_ij = (const float*)d_in[4];
  const float* d_ij = (const float*)d_in[5];
  const float* ln_w = (const float*)d_in[7];
  const float* ln_b = (const float*)d_in[8];
  const float* Wq   = (const float*)d_in[9];
  const float* Wk   = (const float*)d_in[10];
  const float* Wv   = (const float*)d_in[11];
  const float* Wao  = (const float*)d_in[12];
  const float* Wvec = (const float*)d_in[13];
  const float* Wdv  = (const float*)d_in[14];
  const float* bdv  = (const float*)d_in[15];
  const float* Ws   = (const float*)d_in[16];
  const float* bs   = (const float*)d_in[17];
  const float* Wo   = (const float*)d_in[18];
  const float* bo   = (const float*)d_in[19];
  const float* Wf   = (const float*)d_in[20];
  const float* bf_  = (const float*)d_in[21];
  const float* Wsrc = (const float*)d_in[22];
  const float* Wtrg = (const float*)d_in[23];

  char* p = (char*)d_ws;
  auto alloc = [&](size_t bytes) {
    char* r = p; p += (bytes + 255) & ~(size_t)255; return r;
  };
  bf16*  xn_bf   = (bf16*)alloc((size_t)BNc * Hc * 2);
  bf16*  qkv_bf  = (bf16*)alloc((size_t)BNc * 3 * Hc * 2);
  bf16*  attn_bf = (bf16*)alloc((size_t)BNc * Hc * 2);
  float* vbuf    = (float*)alloc((size_t)BNc * Hc * 4);
  bf16*  xagg_bf = (bf16*)alloc((size_t)BNc * Hc * 2);
  float* obuf    = (float*)alloc((size_t)BNc * 3 * Hc * 4);
  bf16*  f_bf    = (bf16*)alloc((size_t)Ec * Hc * 2);
  bf16*  vec_bf  = (bf16*)alloc((size_t)BNc * VDc * Hc * 2);
  bf16*  vpT     = (bf16*)alloc((size_t)Ec * 1024 * 2);     // v1|v3|Tt|Ts
  bf16*  vj_bf   = (bf16*)alloc((size_t)Ec * Hc * 2);
  bf16*  s12_bf  = (bf16*)alloc((size_t)Ec * 2 * Hc * 2);
  bf16*  fW_bf   = (bf16*)alloc((size_t)Ec * Hc * 2);
  bf16*  Wqkv_t  = (bf16*)alloc((size_t)3 * Hc * Hc * 2);
  bf16*  Wao_t   = (bf16*)alloc((size_t)Hc * Hc * 2);
  bf16*  Wdvf_t  = (bf16*)alloc((size_t)2 * Hc * Hc * 2);
  bf16*  Wvt_t   = (bf16*)alloc((size_t)4 * Hc * Hc * 2);
  bf16*  Ws_t    = (bf16*)alloc((size_t)2 * Hc * Hc * 2);
  bf16*  Wo_t    = (bf16*)alloc((size_t)3 * Hc * Hc * 2);
  int*   rowptr  = (int*)alloc(2049 * 4);
  int*   eids    = (int*)alloc(Ec * 4);

  float* out_dx   = (float*)d_out;
  float* out_dvec = (float*)d_out + 524288;
  float* out_df   = (float*)d_out + 4718592;

  // stage 1: csr | wprep | cvt2 | ln  (1 + 2112 + 8192 + 2048 blocks)
  PrepArgs pa;
  pa.ei = ei; pa.rowptr = rowptr; pa.eids = eids;
  pa.wd[0]  = {Wq,   Wqkv_t,           Hc, Hc};
  pa.wd[1]  = {Wk,   Wqkv_t + 65536,   Hc, Hc};
  pa.wd[2]  = {Wv,   Wqkv_t + 131072,  Hc, Hc};
  pa.wd[3]  = {Wao,  Wao_t,            Hc, Hc};
  pa.wd[4]  = {Wdv,  Wdvf_t,           Hc, Hc};
  pa.wd[5]  = {Wf,   Wdvf_t + 65536,   Hc, Hc};
  pa.wd[6]  = {Wvec, Wvt_t,            Hc, 2 * Hc};
  pa.wd[7]  = {Wtrg, Wvt_t + 131072,   Hc, Hc};
  pa.wd[8]  = {Wsrc, Wvt_t + 196608,   Hc, Hc};
  pa.wd[9]  = {Ws,   Ws_t,             Hc, 2 * Hc};
  pa.wd[10] = {Wo,   Wo_t,             Hc, 3 * Hc};
  pa.f_ij = f_ij; pa.f_bf = f_bf; pa.vec = vec; pa.vec_bf = vec_bf;
  pa.x = x; pa.ln_w = ln_w; pa.ln_b = ln_b; pa.xn = xn_bf;
  prep_k<<<12353, 256, 0, stream>>>(pa);

  // stage 2: qkv | vpT GEMMs (96 + 1024 tiles)
  G2Args g2{xn_bf, Wqkv_t, vec_bf, Wvt_t, qkv_bf, vpT};
  gemm2_k<<<1120, 256, 0, stream>>>(g2);

  // stage 3: attention
  attn_mfma_k<<<Bc * NHc, 256, 0, stream>>>(qkv_bf, attn_bf);

  // stage 4: v = attn @ Wao
  mgemm_k<0, float><<<dim3(16, 2), 256, 0, stream>>>(attn_bf, Wao_t, nullptr, vbuf, BNc, Hc, Hc);

  // stage 5: dv|fW GEMM + vj epilogue
  gemm_dvfw_k<<<dim3(128, 4), 256, 0, stream>>>(f_bf, Wdvf_t, bdv, bf_, ei, r_ij,
                                                vbuf, vj_bf, fW_bf);

  // stage 6: s12 GEMM | xagg (512 + 256)
  S6Args s6{vj_bf, Ws_t, bs, s12_bf, rowptr, eids, xagg_bf};
  stage6_k<<<768, 256, 0, stream>>>(s6);

  // stage 7: Wo GEMM | df (96 + 2048)
  S7Args s7{xagg_bf, Wo_t, bo, obuf, vpT, d_ij, fW_bf, ei, out_df};
  stage7_k<<<2144, 256, 0, stream>>>(s7);

  // stage 8: dxsum | dvec_agg (256 + 2048)
  S8Args s8{vpT, obuf, out_dx, vec_bf, s12_bf, d_ij, ei, rowptr, eids, out_dvec};
  stage8_k<<<2304, 256, 0, stream>>>(s8);

  (void)in_sizes; (void)n_in; (void)out_size; (void)ws_size;
}